// Round 1
// baseline (1047.409 us; speedup 1.0000x reference)
//
#include <hip/hip_runtime.h>
#include <math.h>

#define NN 100000
#define NE 1600000

// ---------------- GEMM1: x[N,128] @ W1[128,64] -> out[N,64] ----------------
__global__ void gemm_x_w1(const float* __restrict__ x, const float* __restrict__ W,
                          float* __restrict__ out) {
    __shared__ float Ws[128 * 64];   // 32 KiB
    __shared__ float Xs[4][128];
    for (int i = threadIdx.x; i < 128 * 64; i += blockDim.x) Ws[i] = W[i];
    const int w = threadIdx.x >> 6;
    const int lane = threadIdx.x & 63;
    const int row = blockIdx.x * 4 + w;          // N divisible by 4
    const float* xr = x + (size_t)row * 128;
    Xs[w][lane] = xr[lane];
    Xs[w][lane + 64] = xr[lane + 64];
    __syncthreads();
    float acc = 0.f;
#pragma unroll
    for (int k = 0; k < 128; ++k) acc = fmaf(Xs[w][k], Ws[k * 64 + lane], acc);
    out[(size_t)row * 64 + lane] = acc;
}

// ---------------- GEMM2: h[N,64] @ W2[64,64] -> out[N,64] ----------------
__global__ void gemm_h_w2(const float* __restrict__ h, const float* __restrict__ W,
                          float* __restrict__ out) {
    __shared__ float Ws[64 * 64];    // 16 KiB
    __shared__ float Xs[4][64];
    for (int i = threadIdx.x; i < 64 * 64; i += blockDim.x) Ws[i] = W[i];
    const int w = threadIdx.x >> 6;
    const int lane = threadIdx.x & 63;
    const int row = blockIdx.x * 4 + w;
    Xs[w][lane] = h[(size_t)row * 64 + lane];
    __syncthreads();
    float acc = 0.f;
#pragma unroll
    for (int k = 0; k < 64; ++k) acc = fmaf(Xs[w][k], Ws[k * 64 + lane], acc);
    out[(size_t)row * 64 + lane] = acc;
}

// ---------------- SpMM: one wave per edge, lane = feature ----------------
__global__ void spmm64(const float* __restrict__ feat, const int* __restrict__ es,
                       const int* __restrict__ ed, const float* __restrict__ ew,
                       float* __restrict__ agg) {
    const int wid = (blockIdx.x * blockDim.x + threadIdx.x) >> 6;  // edge id
    const int lane = threadIdx.x & 63;
    const int s = es[wid];
    const int d = ed[wid];
    const float w = ew[wid];
    const float v = feat[(size_t)s * 64 + lane] * w;
    atomicAdd(&agg[(size_t)d * 64 + lane], v);
}

// ---------------- bias + relu ----------------
__global__ void bias_relu(const float* __restrict__ agg, const float* __restrict__ b,
                          float* __restrict__ out) {
    const int i = blockIdx.x * blockDim.x + threadIdx.x;
    const float v = agg[i] + b[i & 63];
    out[i] = v > 0.f ? v : 0.f;
}

// ---------------- head: logits = h2 @ Wl + bl ; logp = log_softmax ----------------
__global__ void head_kernel(const float* __restrict__ h2, const float* __restrict__ Wl,
                            const float* __restrict__ bl, float* __restrict__ logits,
                            float* __restrict__ logp) {
    __shared__ float Ws[64 * 40];    // 10 KiB
    __shared__ float bs[40];
    for (int i = threadIdx.x; i < 64 * 40; i += blockDim.x) Ws[i] = Wl[i];
    if (threadIdx.x < 40) bs[threadIdx.x] = bl[threadIdx.x];
    const int w = threadIdx.x >> 6;
    const int lane = threadIdx.x & 63;
    const int row = blockIdx.x * 4 + w;
    const float hv = h2[(size_t)row * 64 + lane];
    __syncthreads();
    float acc = (lane < 40) ? bs[lane] : 0.f;
#pragma unroll
    for (int k = 0; k < 64; ++k) {
        const float hk = __shfl(hv, k, 64);
        if (lane < 40) acc = fmaf(hk, Ws[k * 40 + lane], acc);
    }
    // wave-level log-softmax over the 40 valid lanes
    float m = (lane < 40) ? acc : -INFINITY;
    for (int off = 32; off; off >>= 1) m = fmaxf(m, __shfl_xor(m, off, 64));
    float e = (lane < 40) ? expf(acc - m) : 0.f;
    float s = e;
    for (int off = 32; off; off >>= 1) s += __shfl_xor(s, off, 64);
    const float lse = logf(s) + m;
    if (lane < 40) {
        logits[(size_t)row * 40 + lane] = acc;
        logp[(size_t)row * 40 + lane] = acc - lse;
    }
}

extern "C" void kernel_launch(void* const* d_in, const int* in_sizes, int n_in,
                              void* d_out, int out_size, void* d_ws, size_t ws_size,
                              hipStream_t stream) {
    const float* x  = (const float*)d_in[0];
    const int*   es = (const int*)  d_in[1];
    const int*   ed = (const int*)  d_in[2];
    const float* ew = (const float*)d_in[3];
    const float* W1 = (const float*)d_in[4];
    const float* b1 = (const float*)d_in[5];
    const float* W2 = (const float*)d_in[6];
    const float* b2 = (const float*)d_in[7];
    const float* Wl = (const float*)d_in[8];
    const float* bl = (const float*)d_in[9];

    float* out    = (float*)d_out;
    float* logp   = out;                          // [N,40]
    float* h1     = logp + (size_t)NN * 40;       // [N,64]
    float* h2     = h1   + (size_t)NN * 64;       // [N,64]
    float* logits = h2   + (size_t)NN * 64;       // [N,40]

    float* ws0 = (float*)d_ws;                    // GEMM output [N,64]
    float* ws1 = ws0 + (size_t)NN * 64;           // aggregation  [N,64]
    const size_t aggBytes = (size_t)NN * 64 * sizeof(float);

    // ---- layer 1 ----
    hipMemsetAsync(ws1, 0, aggBytes, stream);
    gemm_x_w1<<<NN / 4, 256, 0, stream>>>(x, W1, ws0);
    spmm64<<<NE / 4, 256, 0, stream>>>(ws0, es, ed, ew, ws1);
    bias_relu<<<NN * 64 / 256, 256, 0, stream>>>(ws1, b1, h1);

    // ---- layer 2 ----
    gemm_h_w2<<<NN / 4, 256, 0, stream>>>(h1, W2, ws0);
    hipMemsetAsync(ws1, 0, aggBytes, stream);
    spmm64<<<NE / 4, 256, 0, stream>>>(ws0, es, ed, ew, ws1);
    bias_relu<<<NN * 64 / 256, 256, 0, stream>>>(ws1, b2, h2);

    // ---- head ----
    head_kernel<<<NN / 4, 256, 0, stream>>>(h2, Wl, bl, logits, logp);
}

// Round 2
// 998.335 us; speedup vs baseline: 1.0492x; 1.0492x over previous
//
#include <hip/hip_runtime.h>
#include <math.h>

#define NN 100000
#define NE 1600000

// ---------------- GEMM1: x[N,128] @ W1[128,64] -> out[N,64] ----------------
__global__ void gemm_x_w1(const float* __restrict__ x, const float* __restrict__ W,
                          float* __restrict__ out) {
    __shared__ float Ws[128 * 64];   // 32 KiB
    __shared__ float Xs[4][128];
    for (int i = threadIdx.x; i < 128 * 64; i += blockDim.x) Ws[i] = W[i];
    const int w = threadIdx.x >> 6;
    const int lane = threadIdx.x & 63;
    const int row = blockIdx.x * 4 + w;          // N divisible by 4
    const float* xr = x + (size_t)row * 128;
    Xs[w][lane] = xr[lane];
    Xs[w][lane + 64] = xr[lane + 64];
    __syncthreads();
    float acc = 0.f;
#pragma unroll
    for (int k = 0; k < 128; ++k) acc = fmaf(Xs[w][k], Ws[k * 64 + lane], acc);
    out[(size_t)row * 64 + lane] = acc;
}

// ---------------- GEMM2: h[N,64] @ W2[64,64] -> out[N,64] ----------------
__global__ void gemm_h_w2(const float* __restrict__ h, const float* __restrict__ W,
                          float* __restrict__ out) {
    __shared__ float Ws[64 * 64];    // 16 KiB
    __shared__ float Xs[4][64];
    for (int i = threadIdx.x; i < 64 * 64; i += blockDim.x) Ws[i] = W[i];
    const int w = threadIdx.x >> 6;
    const int lane = threadIdx.x & 63;
    const int row = blockIdx.x * 4 + w;
    Xs[w][lane] = h[(size_t)row * 64 + lane];
    __syncthreads();
    float acc = 0.f;
#pragma unroll
    for (int k = 0; k < 64; ++k) acc = fmaf(Xs[w][k], Ws[k * 64 + lane], acc);
    out[(size_t)row * 64 + lane] = acc;
}

// ---------------- CSR build: histogram of destinations ----------------
__global__ void hist_dst(const int* __restrict__ ed, int* __restrict__ counts) {
    const int e = blockIdx.x * blockDim.x + threadIdx.x;
    atomicAdd(&counts[ed[e]], 1);
}

// ---------------- single-block exclusive scan of counts[NN] -> off[NN+1] ----------------
__global__ void scan_block(const int* __restrict__ counts, int* __restrict__ off) {
    __shared__ int psum[1024];
    const int t = threadIdx.x;                 // 1024 threads
    const int per = (NN + 1023) / 1024;        // 98 elements per thread
    const int base = t * per;
    int s = 0;
    for (int i = 0; i < per; ++i) {
        const int idx = base + i;
        if (idx < NN) s += counts[idx];
    }
    psum[t] = s;
    __syncthreads();
    // Hillis-Steele inclusive scan over 1024 partials
    for (int d = 1; d < 1024; d <<= 1) {
        const int v = (t >= d) ? psum[t - d] : 0;
        __syncthreads();
        psum[t] += v;
        __syncthreads();
    }
    int run = (t == 0) ? 0 : psum[t - 1];
    for (int i = 0; i < per; ++i) {
        const int idx = base + i;
        if (idx < NN) {
            off[idx] = run;
            run += counts[idx];
        } else if (idx == NN) {
            off[NN] = run;
        }
    }
}

// ---------------- scatter edges into dest-sorted order ----------------
__global__ void scatter_edges(const int* __restrict__ es, const int* __restrict__ ed,
                              const float* __restrict__ ew, int* __restrict__ cursor,
                              int2* __restrict__ edges2) {
    const int e = blockIdx.x * blockDim.x + threadIdx.x;
    const int d = ed[e];
    const int pos = atomicAdd(&cursor[d], 1);
    edges2[pos] = make_int2(es[e], __float_as_int(ew[e]));
}

// ---------------- CSR SpMM + bias + relu: one wave per dest node ----------------
__global__ __launch_bounds__(256) void spmm_csr(const float* __restrict__ feat,
                                                const int* __restrict__ off,
                                                const int2* __restrict__ edges2,
                                                const float* __restrict__ b,
                                                float* __restrict__ out) {
    const int w = threadIdx.x >> 6;
    const int lane = threadIdx.x & 63;
    const int n = blockIdx.x * 4 + w;          // NN divisible by 4
    const int beg = off[n];
    const int end = off[n + 1];
    float acc = 0.f;
    for (int i = beg; i < end; ++i) {
        const int2 e = edges2[i];              // sequential 8B stream
        acc = fmaf(feat[(size_t)e.x * 64 + lane], __int_as_float(e.y), acc);
    }
    const float v = acc + b[lane];
    out[(size_t)n * 64 + lane] = v > 0.f ? v : 0.f;
}

// ---------------- head: logits = h2 @ Wl + bl ; logp = log_softmax ----------------
__global__ void head_kernel(const float* __restrict__ h2, const float* __restrict__ Wl,
                            const float* __restrict__ bl, float* __restrict__ logits,
                            float* __restrict__ logp) {
    __shared__ float Ws[64 * 40];    // 10 KiB
    __shared__ float bs[40];
    for (int i = threadIdx.x; i < 64 * 40; i += blockDim.x) Ws[i] = Wl[i];
    if (threadIdx.x < 40) bs[threadIdx.x] = bl[threadIdx.x];
    const int w = threadIdx.x >> 6;
    const int lane = threadIdx.x & 63;
    const int row = blockIdx.x * 4 + w;
    const float hv = h2[(size_t)row * 64 + lane];
    __syncthreads();
    float acc = (lane < 40) ? bs[lane] : 0.f;
#pragma unroll
    for (int k = 0; k < 64; ++k) {
        const float hk = __shfl(hv, k, 64);
        if (lane < 40) acc = fmaf(hk, Ws[k * 40 + lane], acc);
    }
    float m = (lane < 40) ? acc : -INFINITY;
    for (int off = 32; off; off >>= 1) m = fmaxf(m, __shfl_xor(m, off, 64));
    float e = (lane < 40) ? expf(acc - m) : 0.f;
    float s = e;
    for (int off = 32; off; off >>= 1) s += __shfl_xor(s, off, 64);
    const float lse = logf(s) + m;
    if (lane < 40) {
        logits[(size_t)row * 40 + lane] = acc;
        logp[(size_t)row * 40 + lane] = acc - lse;
    }
}

extern "C" void kernel_launch(void* const* d_in, const int* in_sizes, int n_in,
                              void* d_out, int out_size, void* d_ws, size_t ws_size,
                              hipStream_t stream) {
    const float* x  = (const float*)d_in[0];
    const int*   es = (const int*)  d_in[1];
    const int*   ed = (const int*)  d_in[2];
    const float* ew = (const float*)d_in[3];
    const float* W1 = (const float*)d_in[4];
    const float* b1 = (const float*)d_in[5];
    const float* W2 = (const float*)d_in[6];
    const float* b2 = (const float*)d_in[7];
    const float* Wl = (const float*)d_in[8];
    const float* bl = (const float*)d_in[9];

    float* out    = (float*)d_out;
    float* logp   = out;                          // [N,40]
    float* h1     = logp + (size_t)NN * 40;       // [N,64]
    float* h2     = h1   + (size_t)NN * 64;       // [N,64]
    float* logits = h2   + (size_t)NN * 64;       // [N,40]

    // workspace layout (all naturally aligned)
    char* wsb = (char*)d_ws;
    float* ws0     = (float*)wsb;                               // [N,64]  25.6 MB
    int2*  edges2  = (int2*)(wsb + (size_t)NN * 64 * 4);        // [E]     12.8 MB
    int*   off     = (int*)((char*)edges2 + (size_t)NE * 8);    // [N+1]
    int*   cursor  = off + (NN + 1);                            // [N] (also counts)

    // ---- build dest-sorted CSR (once, reused by both layers) ----
    hipMemsetAsync(cursor, 0, (size_t)NN * 4, stream);
    hist_dst<<<NE / 256, 256, 0, stream>>>(ed, cursor);
    scan_block<<<1, 1024, 0, stream>>>(cursor, off);
    hipMemcpyAsync(cursor, off, (size_t)NN * 4, hipMemcpyDeviceToDevice, stream);
    scatter_edges<<<NE / 256, 256, 0, stream>>>(es, ed, ew, cursor, edges2);

    // ---- layer 1 ----
    gemm_x_w1<<<NN / 4, 256, 0, stream>>>(x, W1, ws0);
    spmm_csr<<<NN / 4, 256, 0, stream>>>(ws0, off, edges2, b1, h1);

    // ---- layer 2 ----
    gemm_h_w2<<<NN / 4, 256, 0, stream>>>(h1, W2, ws0);
    spmm_csr<<<NN / 4, 256, 0, stream>>>(ws0, off, edges2, b2, h2);

    // ---- head ----
    head_kernel<<<NN / 4, 256, 0, stream>>>(h2, Wl, bl, logits, logp);
}

// Round 3
// 668.497 us; speedup vs baseline: 1.5668x; 1.4934x over previous
//
#include <hip/hip_runtime.h>
#include <math.h>

#define NN 100000
#define NE 1600000
#define SCAN_B 1024
#define NBLK ((NN + SCAN_B - 1) / SCAN_B)   // 98

// ---------------- GEMM1: x[N,128] @ W1[128,64] -> out[N,64] ----------------
__global__ void gemm_x_w1(const float* __restrict__ x, const float* __restrict__ W,
                          float* __restrict__ out) {
    __shared__ float Ws[128 * 64];   // 32 KiB
    __shared__ float Xs[4][128];
    for (int i = threadIdx.x; i < 128 * 64; i += blockDim.x) Ws[i] = W[i];
    const int w = threadIdx.x >> 6;
    const int lane = threadIdx.x & 63;
    const int row = blockIdx.x * 4 + w;          // N divisible by 4
    const float* xr = x + (size_t)row * 128;
    Xs[w][lane] = xr[lane];
    Xs[w][lane + 64] = xr[lane + 64];
    __syncthreads();
    float acc = 0.f;
#pragma unroll
    for (int k = 0; k < 128; ++k) acc = fmaf(Xs[w][k], Ws[k * 64 + lane], acc);
    out[(size_t)row * 64 + lane] = acc;
}

// ---------------- GEMM2: h[N,64] @ W2[64,64] -> out[N,64] ----------------
__global__ void gemm_h_w2(const float* __restrict__ h, const float* __restrict__ W,
                          float* __restrict__ out) {
    __shared__ float Ws[64 * 64];    // 16 KiB
    __shared__ float Xs[4][64];
    for (int i = threadIdx.x; i < 64 * 64; i += blockDim.x) Ws[i] = W[i];
    const int w = threadIdx.x >> 6;
    const int lane = threadIdx.x & 63;
    const int row = blockIdx.x * 4 + w;
    Xs[w][lane] = h[(size_t)row * 64 + lane];
    __syncthreads();
    float acc = 0.f;
#pragma unroll
    for (int k = 0; k < 64; ++k) acc = fmaf(Xs[w][k], Ws[k * 64 + lane], acc);
    out[(size_t)row * 64 + lane] = acc;
}

// ---------------- CSR build: histogram of destinations ----------------
__global__ void hist_dst(const int* __restrict__ ed, int* __restrict__ counts) {
    const int e = blockIdx.x * blockDim.x + threadIdx.x;
    atomicAdd(&counts[ed[e]], 1);
}

// ---------------- hierarchical scan: phase 1 — per-block reduce ----------------
__global__ void scan_phase1(const int* __restrict__ counts, int* __restrict__ partials) {
    const int idx = blockIdx.x * SCAN_B + threadIdx.x;
    int v = (idx < NN) ? counts[idx] : 0;
    for (int off = 32; off; off >>= 1) v += __shfl_xor(v, off, 64);
    __shared__ int wsum[16];
    if ((threadIdx.x & 63) == 0) wsum[threadIdx.x >> 6] = v;
    __syncthreads();
    if (threadIdx.x < 16) {
        int s = wsum[threadIdx.x];
        for (int off = 8; off; off >>= 1) s += __shfl_xor(s, off, 16);
        if (threadIdx.x == 0) partials[blockIdx.x] = s;
    }
}

// ---------------- phase 2 — exclusive scan of the 98 partials ----------------
__global__ void scan_phase2(int* __restrict__ partials) {
    __shared__ int p[128];
    const int t = threadIdx.x;                 // 128 threads
    const int v = (t < NBLK) ? partials[t] : 0;
    p[t] = v;
    __syncthreads();
    for (int d = 1; d < 128; d <<= 1) {
        const int u = (t >= d) ? p[t - d] : 0;
        __syncthreads();
        p[t] += u;
        __syncthreads();
    }
    if (t < NBLK) partials[t] = p[t] - v;      // exclusive
}

// ---------------- phase 3 — block-local exclusive scan + block offset ----------------
__global__ void scan_phase3(const int* __restrict__ counts, const int* __restrict__ partials,
                            int* __restrict__ off) {
    const int b = blockIdx.x;
    const int t = threadIdx.x;
    const int idx = b * SCAN_B + t;
    const int lane = t & 63;
    const int w = t >> 6;
    const int v = (idx < NN) ? counts[idx] : 0;
    int s = v;
    for (int d = 1; d < 64; d <<= 1) {
        const int u = __shfl_up(s, d, 64);
        if (lane >= d) s += u;
    }
    __shared__ int wsum[16];
    if (lane == 63) wsum[w] = s;
    __syncthreads();
    if (t < 16) {
        int ws2 = wsum[t];
        for (int d = 1; d < 16; d <<= 1) {
            const int u = __shfl_up(ws2, d, 16);
            if (t >= d) ws2 += u;
        }
        wsum[t] = ws2;
    }
    __syncthreads();
    const int waveoff = (w == 0) ? 0 : wsum[w - 1];
    if (idx < NN) off[idx] = s - v + waveoff + partials[b];
    if (idx == 0) off[NN] = NE;                // total is a compile-time constant
}

// ---------------- scatter edges into dest-sorted order ----------------
__global__ void scatter_edges(const int* __restrict__ es, const int* __restrict__ ed,
                              const float* __restrict__ ew, int* __restrict__ cursor,
                              int2* __restrict__ edges2) {
    const int e = blockIdx.x * blockDim.x + threadIdx.x;
    const int d = ed[e];
    const int pos = atomicAdd(&cursor[d], 1);
    edges2[pos] = make_int2(es[e], __float_as_int(ew[e]));
}

// ---------------- CSR SpMM + bias + relu: one wave per dest node ----------------
__global__ __launch_bounds__(256) void spmm_csr(const float* __restrict__ feat,
                                                const int* __restrict__ off,
                                                const int2* __restrict__ edges2,
                                                const float* __restrict__ b,
                                                float* __restrict__ out) {
    const int w = threadIdx.x >> 6;
    const int lane = threadIdx.x & 63;
    const int n = blockIdx.x * 4 + w;          // NN divisible by 4
    const int beg = off[n];
    const int end = off[n + 1];
    float acc = 0.f;
    int i = beg;
    for (; i + 3 < end; i += 4) {              // 4 independent gathers in flight
        const int2 e0 = edges2[i];
        const int2 e1 = edges2[i + 1];
        const int2 e2 = edges2[i + 2];
        const int2 e3 = edges2[i + 3];
        const float f0 = feat[(size_t)e0.x * 64 + lane];
        const float f1 = feat[(size_t)e1.x * 64 + lane];
        const float f2 = feat[(size_t)e2.x * 64 + lane];
        const float f3 = feat[(size_t)e3.x * 64 + lane];
        acc = fmaf(f0, __int_as_float(e0.y), acc);
        acc = fmaf(f1, __int_as_float(e1.y), acc);
        acc = fmaf(f2, __int_as_float(e2.y), acc);
        acc = fmaf(f3, __int_as_float(e3.y), acc);
    }
    for (; i < end; ++i) {
        const int2 e = edges2[i];
        acc = fmaf(feat[(size_t)e.x * 64 + lane], __int_as_float(e.y), acc);
    }
    const float v = acc + b[lane];
    out[(size_t)n * 64 + lane] = v > 0.f ? v : 0.f;
}

// ---------------- head: logits = h2 @ Wl + bl ; logp = log_softmax ----------------
__global__ void head_kernel(const float* __restrict__ h2, const float* __restrict__ Wl,
                            const float* __restrict__ bl, float* __restrict__ logits,
                            float* __restrict__ logp) {
    __shared__ float Ws[64 * 40];    // 10 KiB
    __shared__ float bs[40];
    for (int i = threadIdx.x; i < 64 * 40; i += blockDim.x) Ws[i] = Wl[i];
    if (threadIdx.x < 40) bs[threadIdx.x] = bl[threadIdx.x];
    const int w = threadIdx.x >> 6;
    const int lane = threadIdx.x & 63;
    const int row = blockIdx.x * 4 + w;
    const float hv = h2[(size_t)row * 64 + lane];
    __syncthreads();
    float acc = (lane < 40) ? bs[lane] : 0.f;
#pragma unroll
    for (int k = 0; k < 64; ++k) {
        const float hk = __shfl(hv, k, 64);
        if (lane < 40) acc = fmaf(hk, Ws[k * 40 + lane], acc);
    }
    float m = (lane < 40) ? acc : -INFINITY;
    for (int off = 32; off; off >>= 1) m = fmaxf(m, __shfl_xor(m, off, 64));
    float e = (lane < 40) ? expf(acc - m) : 0.f;
    float s = e;
    for (int off = 32; off; off >>= 1) s += __shfl_xor(s, off, 64);
    const float lse = logf(s) + m;
    if (lane < 40) {
        logits[(size_t)row * 40 + lane] = acc;
        logp[(size_t)row * 40 + lane] = acc - lse;
    }
}

extern "C" void kernel_launch(void* const* d_in, const int* in_sizes, int n_in,
                              void* d_out, int out_size, void* d_ws, size_t ws_size,
                              hipStream_t stream) {
    const float* x  = (const float*)d_in[0];
    const int*   es = (const int*)  d_in[1];
    const int*   ed = (const int*)  d_in[2];
    const float* ew = (const float*)d_in[3];
    const float* W1 = (const float*)d_in[4];
    const float* b1 = (const float*)d_in[5];
    const float* W2 = (const float*)d_in[6];
    const float* b2 = (const float*)d_in[7];
    const float* Wl = (const float*)d_in[8];
    const float* bl = (const float*)d_in[9];

    float* out    = (float*)d_out;
    float* logp   = out;                          // [N,40]
    float* h1     = logp + (size_t)NN * 40;       // [N,64]
    float* h2     = h1   + (size_t)NN * 64;       // [N,64]
    float* logits = h2   + (size_t)NN * 64;       // [N,40]

    // workspace layout (all naturally aligned)
    char* wsb = (char*)d_ws;
    float* ws0     = (float*)wsb;                               // [N,64]  25.6 MB
    int2*  edges2  = (int2*)(wsb + (size_t)NN * 64 * 4);        // [E]     12.8 MB
    int*   off     = (int*)((char*)edges2 + (size_t)NE * 8);    // [N+1]
    int*   cursor  = off + (NN + 1);                            // [N] (counts, then cursors)
    int*   partials = cursor + NN;                              // [NBLK]

    // ---- build dest-sorted CSR (once, reused by both layers) ----
    hipMemsetAsync(cursor, 0, (size_t)NN * 4, stream);
    hist_dst<<<NE / 256, 256, 0, stream>>>(ed, cursor);
    scan_phase1<<<NBLK, SCAN_B, 0, stream>>>(cursor, partials);
    scan_phase2<<<1, 128, 0, stream>>>(partials);
    scan_phase3<<<NBLK, SCAN_B, 0, stream>>>(cursor, partials, off);
    hipMemcpyAsync(cursor, off, (size_t)NN * 4, hipMemcpyDeviceToDevice, stream);
    scatter_edges<<<NE / 256, 256, 0, stream>>>(es, ed, ew, cursor, edges2);

    // ---- layer 1 ----
    gemm_x_w1<<<NN / 4, 256, 0, stream>>>(x, W1, ws0);
    spmm_csr<<<NN / 4, 256, 0, stream>>>(ws0, off, edges2, b1, h1);

    // ---- layer 2 ----
    gemm_h_w2<<<NN / 4, 256, 0, stream>>>(h1, W2, ws0);
    spmm_csr<<<NN / 4, 256, 0, stream>>>(ws0, off, edges2, b2, h2);

    // ---- head ----
    head_kernel<<<NN / 4, 256, 0, stream>>>(h2, Wl, bl, logits, logp);
}

// Round 4
// 595.403 us; speedup vs baseline: 1.7592x; 1.1228x over previous
//
#include <hip/hip_runtime.h>
#include <math.h>

#define NN 100000
#define NE 1600000
#define SCAN_B 1024
#define NBLK ((NN + SCAN_B - 1) / SCAN_B)   // 98

// ============ GEMM1: x[N,128] @ W1[128,64] -> out[N,64] ============
// 64-row tile per block, 256 threads, each thread computes 4 rows x 4 cols.
// W transposed in LDS (Wt[c][k], pad 132); X staged in two K-halves (pad 68).
__global__ __launch_bounds__(256) void gemm1_tile(const float* __restrict__ x,
                                                  const float* __restrict__ W,
                                                  float* __restrict__ out) {
    __shared__ float Wt[64 * 132];     // 33792 B
    __shared__ float Xs[64 * 68];      // 17408 B   (total 50 KB -> 3 blocks/CU)
    const int tid = threadIdx.x;
    const int row0 = blockIdx.x * 64;
    // stage W transposed: W[k][c] -> Wt[c*132 + k]
    for (int i = tid; i < 128 * 64; i += 256) {
        const int k = i >> 6, c = i & 63;
        Wt[c * 132 + k] = W[i];
    }
    const int tc = tid & 15;           // col group (4 cols)
    const int tr = tid >> 4;           // row group (4 rows)
    float acc[4][4] = {};
    const float* wb = &Wt[(tc * 4) * 132];
    for (int kh = 0; kh < 2; ++kh) {
        __syncthreads();               // Wt ready (kh=0) / prev readers done (kh=1)
        for (int i = tid; i < 64 * 16; i += 256) {     // 64 rows x 16 float4
            const int r = i >> 4, kq = i & 15;
            const int row = row0 + r;
            float4 v = make_float4(0.f, 0.f, 0.f, 0.f);
            if (row < NN) v = *(const float4*)(x + (size_t)row * 128 + kh * 64 + kq * 4);
            *(float4*)(&Xs[r * 68 + kq * 4]) = v;
        }
        __syncthreads();
        const float* xb = &Xs[(tr * 4) * 68];
        for (int k = 0; k < 64; k += 4) {
            float4 xv[4], wv[4];
#pragma unroll
            for (int r = 0; r < 4; ++r) xv[r] = *(const float4*)(xb + r * 68 + k);
#pragma unroll
            for (int c = 0; c < 4; ++c) wv[c] = *(const float4*)(wb + c * 132 + kh * 64 + k);
#pragma unroll
            for (int r = 0; r < 4; ++r)
#pragma unroll
                for (int c = 0; c < 4; ++c) {
                    acc[r][c] = fmaf(xv[r].x, wv[c].x, acc[r][c]);
                    acc[r][c] = fmaf(xv[r].y, wv[c].y, acc[r][c]);
                    acc[r][c] = fmaf(xv[r].z, wv[c].z, acc[r][c]);
                    acc[r][c] = fmaf(xv[r].w, wv[c].w, acc[r][c]);
                }
        }
    }
#pragma unroll
    for (int r = 0; r < 4; ++r) {
        const int row = row0 + tr * 4 + r;
        if (row < NN) {
            const float4 v = make_float4(acc[r][0], acc[r][1], acc[r][2], acc[r][3]);
            *(float4*)(out + (size_t)row * 64 + tc * 4) = v;
        }
    }
}

// ============ GEMM2: h[N,64] @ W2[64,64] -> out[N,64] ============
__global__ __launch_bounds__(256) void gemm2_tile(const float* __restrict__ h,
                                                  const float* __restrict__ W,
                                                  float* __restrict__ out) {
    __shared__ float Wt[64 * 68];      // 17408 B
    __shared__ float Xs[64 * 68];      // 17408 B  (34 KB -> 4 blocks/CU)
    const int tid = threadIdx.x;
    const int row0 = blockIdx.x * 64;
    for (int i = tid; i < 64 * 64; i += 256) {
        const int k = i >> 6, c = i & 63;
        Wt[c * 68 + k] = W[i];
    }
    for (int i = tid; i < 64 * 16; i += 256) {
        const int r = i >> 4, kq = i & 15;
        const int row = row0 + r;
        float4 v = make_float4(0.f, 0.f, 0.f, 0.f);
        if (row < NN) v = *(const float4*)(h + (size_t)row * 64 + kq * 4);
        *(float4*)(&Xs[r * 68 + kq * 4]) = v;
    }
    __syncthreads();
    const int tc = tid & 15;
    const int tr = tid >> 4;
    float acc[4][4] = {};
    const float* xb = &Xs[(tr * 4) * 68];
    const float* wb = &Wt[(tc * 4) * 68];
    for (int k = 0; k < 64; k += 4) {
        float4 xv[4], wv[4];
#pragma unroll
        for (int r = 0; r < 4; ++r) xv[r] = *(const float4*)(xb + r * 68 + k);
#pragma unroll
        for (int c = 0; c < 4; ++c) wv[c] = *(const float4*)(wb + c * 68 + k);
#pragma unroll
        for (int r = 0; r < 4; ++r)
#pragma unroll
            for (int c = 0; c < 4; ++c) {
                acc[r][c] = fmaf(xv[r].x, wv[c].x, acc[r][c]);
                acc[r][c] = fmaf(xv[r].y, wv[c].y, acc[r][c]);
                acc[r][c] = fmaf(xv[r].z, wv[c].z, acc[r][c]);
                acc[r][c] = fmaf(xv[r].w, wv[c].w, acc[r][c]);
            }
    }
#pragma unroll
    for (int r = 0; r < 4; ++r) {
        const int row = row0 + tr * 4 + r;
        if (row < NN) {
            const float4 v = make_float4(acc[r][0], acc[r][1], acc[r][2], acc[r][3]);
            *(float4*)(out + (size_t)row * 64 + tc * 4) = v;
        }
    }
}

// ---------------- CSR build: histogram of destinations ----------------
__global__ void hist_dst(const int* __restrict__ ed, int* __restrict__ counts) {
    const int e = blockIdx.x * blockDim.x + threadIdx.x;
    atomicAdd(&counts[ed[e]], 1);
}

// ---------------- hierarchical scan: phase 1 — per-block reduce ----------------
__global__ void scan_phase1(const int* __restrict__ counts, int* __restrict__ partials) {
    const int idx = blockIdx.x * SCAN_B + threadIdx.x;
    int v = (idx < NN) ? counts[idx] : 0;
    for (int off = 32; off; off >>= 1) v += __shfl_xor(v, off, 64);
    __shared__ int wsum[16];
    if ((threadIdx.x & 63) == 0) wsum[threadIdx.x >> 6] = v;
    __syncthreads();
    if (threadIdx.x < 16) {
        int s = wsum[threadIdx.x];
        for (int off = 8; off; off >>= 1) s += __shfl_xor(s, off, 16);
        if (threadIdx.x == 0) partials[blockIdx.x] = s;
    }
}

// ---------------- phase 2 — exclusive scan of the 98 partials ----------------
__global__ void scan_phase2(int* __restrict__ partials) {
    __shared__ int p[128];
    const int t = threadIdx.x;                 // 128 threads
    const int v = (t < NBLK) ? partials[t] : 0;
    p[t] = v;
    __syncthreads();
    for (int d = 1; d < 128; d <<= 1) {
        const int u = (t >= d) ? p[t - d] : 0;
        __syncthreads();
        p[t] += u;
        __syncthreads();
    }
    if (t < NBLK) partials[t] = p[t] - v;      // exclusive
}

// ---------------- phase 3 — block-local exclusive scan + block offset ----------------
__global__ void scan_phase3(const int* __restrict__ counts, const int* __restrict__ partials,
                            int* __restrict__ off) {
    const int b = blockIdx.x;
    const int t = threadIdx.x;
    const int idx = b * SCAN_B + t;
    const int lane = t & 63;
    const int w = t >> 6;
    const int v = (idx < NN) ? counts[idx] : 0;
    int s = v;
    for (int d = 1; d < 64; d <<= 1) {
        const int u = __shfl_up(s, d, 64);
        if (lane >= d) s += u;
    }
    __shared__ int wsum[16];
    if (lane == 63) wsum[w] = s;
    __syncthreads();
    if (t < 16) {
        int ws2 = wsum[t];
        for (int d = 1; d < 16; d <<= 1) {
            const int u = __shfl_up(ws2, d, 16);
            if (t >= d) ws2 += u;
        }
        wsum[t] = ws2;
    }
    __syncthreads();
    const int waveoff = (w == 0) ? 0 : wsum[w - 1];
    if (idx < NN) off[idx] = s - v + waveoff + partials[b];
    if (idx == 0) off[NN] = NE;                // total is a compile-time constant
}

// ---------------- scatter edges into dest-sorted order ----------------
__global__ void scatter_edges(const int* __restrict__ es, const int* __restrict__ ed,
                              const float* __restrict__ ew, int* __restrict__ cursor,
                              int2* __restrict__ edges2) {
    const int e = blockIdx.x * blockDim.x + threadIdx.x;
    const int d = ed[e];
    const int pos = atomicAdd(&cursor[d], 1);
    edges2[pos] = make_int2(es[e], __float_as_int(ew[e]));
}

// ---------------- CSR SpMM + bias + relu: one wave per dest node ----------------
__global__ __launch_bounds__(256) void spmm_csr(const float* __restrict__ feat,
                                                const int* __restrict__ off,
                                                const int2* __restrict__ edges2,
                                                const float* __restrict__ b,
                                                float* __restrict__ out) {
    const int w = threadIdx.x >> 6;
    const int lane = threadIdx.x & 63;
    const int n = blockIdx.x * 4 + w;          // NN divisible by 4
    const int beg = off[n];
    const int end = off[n + 1];
    float acc = 0.f;
    int i = beg;
    for (; i + 3 < end; i += 4) {              // 4 independent gathers in flight
        const int2 e0 = edges2[i];
        const int2 e1 = edges2[i + 1];
        const int2 e2 = edges2[i + 2];
        const int2 e3 = edges2[i + 3];
        const float f0 = feat[(size_t)e0.x * 64 + lane];
        const float f1 = feat[(size_t)e1.x * 64 + lane];
        const float f2 = feat[(size_t)e2.x * 64 + lane];
        const float f3 = feat[(size_t)e3.x * 64 + lane];
        acc = fmaf(f0, __int_as_float(e0.y), acc);
        acc = fmaf(f1, __int_as_float(e1.y), acc);
        acc = fmaf(f2, __int_as_float(e2.y), acc);
        acc = fmaf(f3, __int_as_float(e3.y), acc);
    }
    for (; i < end; ++i) {
        const int2 e = edges2[i];
        acc = fmaf(feat[(size_t)e.x * 64 + lane], __int_as_float(e.y), acc);
    }
    const float v = acc + b[lane];
    out[(size_t)n * 64 + lane] = v > 0.f ? v : 0.f;
}

// ---------------- head: logits = h2 @ Wl + bl ; logp = log_softmax ----------------
__global__ void head_kernel(const float* __restrict__ h2, const float* __restrict__ Wl,
                            const float* __restrict__ bl, float* __restrict__ logits,
                            float* __restrict__ logp) {
    __shared__ float Ws[64 * 40];    // 10 KiB
    __shared__ float bs[40];
    for (int i = threadIdx.x; i < 64 * 40; i += blockDim.x) Ws[i] = Wl[i];
    if (threadIdx.x < 40) bs[threadIdx.x] = bl[threadIdx.x];
    const int w = threadIdx.x >> 6;
    const int lane = threadIdx.x & 63;
    const int row = blockIdx.x * 4 + w;
    const float hv = h2[(size_t)row * 64 + lane];
    __syncthreads();
    float acc = (lane < 40) ? bs[lane] : 0.f;
#pragma unroll
    for (int k = 0; k < 64; ++k) {
        const float hk = __shfl(hv, k, 64);
        if (lane < 40) acc = fmaf(hk, Ws[k * 40 + lane], acc);
    }
    float m = (lane < 40) ? acc : -INFINITY;
    for (int off = 32; off; off >>= 1) m = fmaxf(m, __shfl_xor(m, off, 64));
    float e = (lane < 40) ? expf(acc - m) : 0.f;
    float s = e;
    for (int off = 32; off; off >>= 1) s += __shfl_xor(s, off, 64);
    const float lse = logf(s) + m;
    if (lane < 40) {
        logits[(size_t)row * 40 + lane] = acc;
        logp[(size_t)row * 40 + lane] = acc - lse;
    }
}

extern "C" void kernel_launch(void* const* d_in, const int* in_sizes, int n_in,
                              void* d_out, int out_size, void* d_ws, size_t ws_size,
                              hipStream_t stream) {
    const float* x  = (const float*)d_in[0];
    const int*   es = (const int*)  d_in[1];
    const int*   ed = (const int*)  d_in[2];
    const float* ew = (const float*)d_in[3];
    const float* W1 = (const float*)d_in[4];
    const float* b1 = (const float*)d_in[5];
    const float* W2 = (const float*)d_in[6];
    const float* b2 = (const float*)d_in[7];
    const float* Wl = (const float*)d_in[8];
    const float* bl = (const float*)d_in[9];

    float* out    = (float*)d_out;
    float* logp   = out;                          // [N,40]
    float* h1     = logp + (size_t)NN * 40;       // [N,64]
    float* h2     = h1   + (size_t)NN * 64;       // [N,64]
    float* logits = h2   + (size_t)NN * 64;       // [N,40]

    // workspace layout (all naturally aligned)
    char* wsb = (char*)d_ws;
    float* ws0     = (float*)wsb;                               // [N,64]  25.6 MB
    int2*  edges2  = (int2*)(wsb + (size_t)NN * 64 * 4);        // [E]     12.8 MB
    int*   off     = (int*)((char*)edges2 + (size_t)NE * 8);    // [N+1]
    int*   cursor  = off + (NN + 1);                            // [N] (counts, then cursors)
    int*   partials = cursor + NN;                              // [NBLK]

    const int gemmGrid = (NN + 63) / 64;         // 1563

    // ---- build dest-sorted CSR (once, reused by both layers) ----
    hipMemsetAsync(cursor, 0, (size_t)NN * 4, stream);
    hist_dst<<<NE / 256, 256, 0, stream>>>(ed, cursor);
    scan_phase1<<<NBLK, SCAN_B, 0, stream>>>(cursor, partials);
    scan_phase2<<<1, 128, 0, stream>>>(partials);
    scan_phase3<<<NBLK, SCAN_B, 0, stream>>>(cursor, partials, off);
    hipMemcpyAsync(cursor, off, (size_t)NN * 4, hipMemcpyDeviceToDevice, stream);
    scatter_edges<<<NE / 256, 256, 0, stream>>>(es, ed, ew, cursor, edges2);

    // ---- layer 1 ----
    gemm1_tile<<<gemmGrid, 256, 0, stream>>>(x, W1, ws0);
    spmm_csr<<<NN / 4, 256, 0, stream>>>(ws0, off, edges2, b1, h1);

    // ---- layer 2 ----
    gemm2_tile<<<gemmGrid, 256, 0, stream>>>(h1, W2, ws0);
    spmm_csr<<<NN / 4, 256, 0, stream>>>(ws0, off, edges2, b2, h2);

    // ---- head ----
    head_kernel<<<NN / 4, 256, 0, stream>>>(h2, Wl, bl, logits, logp);
}

// Round 5
// 555.110 us; speedup vs baseline: 1.8868x; 1.0726x over previous
//
#include <hip/hip_runtime.h>
#include <math.h>

#define NN 100000
#define NE 1600000
#define SCAN_B 1024
#define NBLK ((NN + SCAN_B - 1) / SCAN_B)   // 98
#define BSHIFT 9
#define NBUCK ((NN + (1 << BSHIFT) - 1) >> BSHIFT)   // 196

// ============ GEMM1: x[N,128] @ W1[128,64] -> out[N,64] ============
__global__ __launch_bounds__(256) void gemm1_tile(const float* __restrict__ x,
                                                  const float* __restrict__ W,
                                                  float* __restrict__ out) {
    __shared__ float Wt[64 * 132];     // 33792 B
    __shared__ float Xs[64 * 68];      // 17408 B   (total 50 KB -> 3 blocks/CU)
    const int tid = threadIdx.x;
    const int row0 = blockIdx.x * 64;
    for (int i = tid; i < 128 * 64; i += 256) {
        const int k = i >> 6, c = i & 63;
        Wt[c * 132 + k] = W[i];
    }
    const int tc = tid & 15;
    const int tr = tid >> 4;
    float acc[4][4] = {};
    const float* wb = &Wt[(tc * 4) * 132];
    for (int kh = 0; kh < 2; ++kh) {
        __syncthreads();
        for (int i = tid; i < 64 * 16; i += 256) {
            const int r = i >> 4, kq = i & 15;
            const int row = row0 + r;
            float4 v = make_float4(0.f, 0.f, 0.f, 0.f);
            if (row < NN) v = *(const float4*)(x + (size_t)row * 128 + kh * 64 + kq * 4);
            *(float4*)(&Xs[r * 68 + kq * 4]) = v;
        }
        __syncthreads();
        const float* xb = &Xs[(tr * 4) * 68];
        for (int k = 0; k < 64; k += 4) {
            float4 xv[4], wv[4];
#pragma unroll
            for (int r = 0; r < 4; ++r) xv[r] = *(const float4*)(xb + r * 68 + k);
#pragma unroll
            for (int c = 0; c < 4; ++c) wv[c] = *(const float4*)(wb + c * 132 + kh * 64 + k);
#pragma unroll
            for (int r = 0; r < 4; ++r)
#pragma unroll
                for (int c = 0; c < 4; ++c) {
                    acc[r][c] = fmaf(xv[r].x, wv[c].x, acc[r][c]);
                    acc[r][c] = fmaf(xv[r].y, wv[c].y, acc[r][c]);
                    acc[r][c] = fmaf(xv[r].z, wv[c].z, acc[r][c]);
                    acc[r][c] = fmaf(xv[r].w, wv[c].w, acc[r][c]);
                }
        }
    }
#pragma unroll
    for (int r = 0; r < 4; ++r) {
        const int row = row0 + tr * 4 + r;
        if (row < NN) {
            const float4 v = make_float4(acc[r][0], acc[r][1], acc[r][2], acc[r][3]);
            *(float4*)(out + (size_t)row * 64 + tc * 4) = v;
        }
    }
}

// ============ GEMM2: h[N,64] @ W2[64,64] -> out[N,64] ============
__global__ __launch_bounds__(256) void gemm2_tile(const float* __restrict__ h,
                                                  const float* __restrict__ W,
                                                  float* __restrict__ out) {
    __shared__ float Wt[64 * 68];
    __shared__ float Xs[64 * 68];
    const int tid = threadIdx.x;
    const int row0 = blockIdx.x * 64;
    for (int i = tid; i < 64 * 64; i += 256) {
        const int k = i >> 6, c = i & 63;
        Wt[c * 68 + k] = W[i];
    }
    for (int i = tid; i < 64 * 16; i += 256) {
        const int r = i >> 4, kq = i & 15;
        const int row = row0 + r;
        float4 v = make_float4(0.f, 0.f, 0.f, 0.f);
        if (row < NN) v = *(const float4*)(h + (size_t)row * 64 + kq * 4);
        *(float4*)(&Xs[r * 68 + kq * 4]) = v;
    }
    __syncthreads();
    const int tc = tid & 15;
    const int tr = tid >> 4;
    float acc[4][4] = {};
    const float* xb = &Xs[(tr * 4) * 68];
    const float* wb = &Wt[(tc * 4) * 68];
    for (int k = 0; k < 64; k += 4) {
        float4 xv[4], wv[4];
#pragma unroll
        for (int r = 0; r < 4; ++r) xv[r] = *(const float4*)(xb + r * 68 + k);
#pragma unroll
        for (int c = 0; c < 4; ++c) wv[c] = *(const float4*)(wb + c * 68 + k);
#pragma unroll
        for (int r = 0; r < 4; ++r)
#pragma unroll
            for (int c = 0; c < 4; ++c) {
                acc[r][c] = fmaf(xv[r].x, wv[c].x, acc[r][c]);
                acc[r][c] = fmaf(xv[r].y, wv[c].y, acc[r][c]);
                acc[r][c] = fmaf(xv[r].z, wv[c].z, acc[r][c]);
                acc[r][c] = fmaf(xv[r].w, wv[c].w, acc[r][c]);
            }
    }
#pragma unroll
    for (int r = 0; r < 4; ++r) {
        const int row = row0 + tr * 4 + r;
        if (row < NN) {
            const float4 v = make_float4(acc[r][0], acc[r][1], acc[r][2], acc[r][3]);
            *(float4*)(out + (size_t)row * 64 + tc * 4) = v;
        }
    }
}

// ---------------- CSR build: histogram of destinations ----------------
__global__ void hist_dst(const int* __restrict__ ed, int* __restrict__ counts) {
    const int e = blockIdx.x * blockDim.x + threadIdx.x;
    atomicAdd(&counts[ed[e]], 1);
}

// ---------------- hierarchical scan: phase 1 — per-block reduce ----------------
__global__ void scan_phase1(const int* __restrict__ counts, int* __restrict__ partials) {
    const int idx = blockIdx.x * SCAN_B + threadIdx.x;
    int v = (idx < NN) ? counts[idx] : 0;
    for (int off = 32; off; off >>= 1) v += __shfl_xor(v, off, 64);
    __shared__ int wsum[16];
    if ((threadIdx.x & 63) == 0) wsum[threadIdx.x >> 6] = v;
    __syncthreads();
    if (threadIdx.x < 16) {
        int s = wsum[threadIdx.x];
        for (int off = 8; off; off >>= 1) s += __shfl_xor(s, off, 16);
        if (threadIdx.x == 0) partials[blockIdx.x] = s;
    }
}

// ---------------- phase 2 — exclusive scan of the 98 partials ----------------
__global__ void scan_phase2(int* __restrict__ partials) {
    __shared__ int p[128];
    const int t = threadIdx.x;
    const int v = (t < NBLK) ? partials[t] : 0;
    p[t] = v;
    __syncthreads();
    for (int d = 1; d < 128; d <<= 1) {
        const int u = (t >= d) ? p[t - d] : 0;
        __syncthreads();
        p[t] += u;
        __syncthreads();
    }
    if (t < NBLK) partials[t] = p[t] - v;
}

// ---------------- phase 3 — block-local exclusive scan + block offset ----------------
__global__ void scan_phase3(const int* __restrict__ counts, const int* __restrict__ partials,
                            int* __restrict__ off) {
    const int b = blockIdx.x;
    const int t = threadIdx.x;
    const int idx = b * SCAN_B + t;
    const int lane = t & 63;
    const int w = t >> 6;
    const int v = (idx < NN) ? counts[idx] : 0;
    int s = v;
    for (int d = 1; d < 64; d <<= 1) {
        const int u = __shfl_up(s, d, 64);
        if (lane >= d) s += u;
    }
    __shared__ int wsum[16];
    if (lane == 63) wsum[w] = s;
    __syncthreads();
    if (t < 16) {
        int ws2 = wsum[t];
        for (int d = 1; d < 16; d <<= 1) {
            const int u = __shfl_up(ws2, d, 16);
            if (t >= d) ws2 += u;
        }
        wsum[t] = ws2;
    }
    __syncthreads();
    const int waveoff = (w == 0) ? 0 : wsum[w - 1];
    if (idx < NN) off[idx] = s - v + waveoff + partials[b];
    if (idx == 0) off[NN] = NE;
}

// ---------------- init coarse-bucket cursors from off ----------------
__global__ void init_bcur(const int* __restrict__ off, int* __restrict__ bcur) {
    const int b = threadIdx.x;
    if (b < NBUCK) bcur[b] = off[b << BSHIFT];
}

// ---------------- pass 1: bin edges into 512-node buckets (locality-friendly) ----------------
__global__ __launch_bounds__(256) void bin_edges(const int* __restrict__ es,
                                                 const int* __restrict__ ed,
                                                 const float* __restrict__ ew,
                                                 int* __restrict__ bcur,
                                                 int2* __restrict__ srcw2b,
                                                 int* __restrict__ dstb) {
    __shared__ int hist[NBUCK];
    __shared__ int base[NBUCK];
    const int tid = threadIdx.x;
    const int e0 = blockIdx.x * 4096;
    for (int i = tid; i < NBUCK; i += 256) hist[i] = 0;
    __syncthreads();
    int d[16];
#pragma unroll
    for (int j = 0; j < 16; ++j) {
        const int e = e0 + j * 256 + tid;
        d[j] = (e < NE) ? ed[e] : -1;
        if (d[j] >= 0) atomicAdd(&hist[d[j] >> BSHIFT], 1);
    }
    __syncthreads();
    for (int i = tid; i < NBUCK; i += 256) base[i] = atomicAdd(&bcur[i], hist[i]);
    __syncthreads();
    for (int i = tid; i < NBUCK; i += 256) hist[i] = 0;
    __syncthreads();
#pragma unroll
    for (int j = 0; j < 16; ++j) {
        const int e = e0 + j * 256 + tid;
        if (d[j] >= 0) {
            const int b = d[j] >> BSHIFT;
            const int l = atomicAdd(&hist[b], 1);
            const int p = base[b] + l;
            srcw2b[p] = make_int2(es[e], __float_as_int(ew[e]));
            dstb[p] = d[j];
        }
    }
}

// ---------------- pass 2: place within L2-resident bucket windows ----------------
__global__ void place_edges(const int2* __restrict__ srcw2b, const int* __restrict__ dstb,
                            int* __restrict__ cursor, int2* __restrict__ edges2) {
    const int e = blockIdx.x * blockDim.x + threadIdx.x;
    if (e < NE) {
        const int dd = dstb[e];
        const int p = atomicAdd(&cursor[dd], 1);
        edges2[p] = srcw2b[e];
    }
}

// ---------------- CSR SpMM + bias + relu: one wave per dest node ----------------
__global__ __launch_bounds__(256) void spmm_csr(const float* __restrict__ feat,
                                                const int* __restrict__ off,
                                                const int2* __restrict__ edges2,
                                                const float* __restrict__ b,
                                                float* __restrict__ out) {
    const int w = threadIdx.x >> 6;
    const int lane = threadIdx.x & 63;
    const int n = blockIdx.x * 4 + w;
    const int beg = off[n];
    const int end = off[n + 1];
    float acc = 0.f;
    int i = beg;
    for (; i + 3 < end; i += 4) {
        const int2 e0 = edges2[i];
        const int2 e1 = edges2[i + 1];
        const int2 e2 = edges2[i + 2];
        const int2 e3 = edges2[i + 3];
        const float f0 = feat[(size_t)e0.x * 64 + lane];
        const float f1 = feat[(size_t)e1.x * 64 + lane];
        const float f2 = feat[(size_t)e2.x * 64 + lane];
        const float f3 = feat[(size_t)e3.x * 64 + lane];
        acc = fmaf(f0, __int_as_float(e0.y), acc);
        acc = fmaf(f1, __int_as_float(e1.y), acc);
        acc = fmaf(f2, __int_as_float(e2.y), acc);
        acc = fmaf(f3, __int_as_float(e3.y), acc);
    }
    for (; i < end; ++i) {
        const int2 e = edges2[i];
        acc = fmaf(feat[(size_t)e.x * 64 + lane], __int_as_float(e.y), acc);
    }
    const float v = acc + b[lane];
    out[(size_t)n * 64 + lane] = v > 0.f ? v : 0.f;
}

// ---------------- head: logits = h2 @ Wl + bl ; logp = log_softmax ----------------
__global__ void head_kernel(const float* __restrict__ h2, const float* __restrict__ Wl,
                            const float* __restrict__ bl, float* __restrict__ logits,
                            float* __restrict__ logp) {
    __shared__ float Ws[64 * 40];
    __shared__ float bs[40];
    for (int i = threadIdx.x; i < 64 * 40; i += blockDim.x) Ws[i] = Wl[i];
    if (threadIdx.x < 40) bs[threadIdx.x] = bl[threadIdx.x];
    const int w = threadIdx.x >> 6;
    const int lane = threadIdx.x & 63;
    const int row = blockIdx.x * 4 + w;
    const float hv = h2[(size_t)row * 64 + lane];
    __syncthreads();
    float acc = (lane < 40) ? bs[lane] : 0.f;
#pragma unroll
    for (int k = 0; k < 64; ++k) {
        const float hk = __shfl(hv, k, 64);
        if (lane < 40) acc = fmaf(hk, Ws[k * 40 + lane], acc);
    }
    float m = (lane < 40) ? acc : -INFINITY;
    for (int off = 32; off; off >>= 1) m = fmaxf(m, __shfl_xor(m, off, 64));
    float e = (lane < 40) ? expf(acc - m) : 0.f;
    float s = e;
    for (int off = 32; off; off >>= 1) s += __shfl_xor(s, off, 64);
    const float lse = logf(s) + m;
    if (lane < 40) {
        logits[(size_t)row * 40 + lane] = acc;
        logp[(size_t)row * 40 + lane] = acc - lse;
    }
}

extern "C" void kernel_launch(void* const* d_in, const int* in_sizes, int n_in,
                              void* d_out, int out_size, void* d_ws, size_t ws_size,
                              hipStream_t stream) {
    const float* x  = (const float*)d_in[0];
    const int*   es = (const int*)  d_in[1];
    const int*   ed = (const int*)  d_in[2];
    const float* ew = (const float*)d_in[3];
    const float* W1 = (const float*)d_in[4];
    const float* b1 = (const float*)d_in[5];
    const float* W2 = (const float*)d_in[6];
    const float* b2 = (const float*)d_in[7];
    const float* Wl = (const float*)d_in[8];
    const float* bl = (const float*)d_in[9];

    float* out    = (float*)d_out;
    float* logp   = out;                          // [N,40]
    float* h1     = logp + (size_t)NN * 40;       // [N,64]
    float* h2     = h1   + (size_t)NN * 64;       // [N,64]
    float* logits = h2   + (size_t)NN * 64;       // [N,40]

    // workspace layout
    char* wsb = (char*)d_ws;
    float* ws0     = (float*)wsb;                               // [N,64] 25.6 MB (GEMM out)
    int2*  srcw2b  = (int2*)wsb;                                // binned edges  (overlays ws0)
    int*   dstb    = (int*)(wsb + (size_t)NE * 8);              // binned dsts   (overlays ws0)
    int2*  edges2  = (int2*)(wsb + (size_t)NN * 64 * 4);        // [E] 12.8 MB
    int*   off     = (int*)((char*)edges2 + (size_t)NE * 8);    // [N+1]
    int*   cursor  = off + (NN + 1);                            // [N]
    int*   partials = cursor + NN;                              // [NBLK]
    int*   bcur    = partials + NBLK;                           // [NBUCK]

    const int gemmGrid = (NN + 63) / 64;

    // ---- build dest-sorted CSR (once, reused by both layers) ----
    hipMemsetAsync(cursor, 0, (size_t)NN * 4, stream);
    hist_dst<<<NE / 256, 256, 0, stream>>>(ed, cursor);
    scan_phase1<<<NBLK, SCAN_B, 0, stream>>>(cursor, partials);
    scan_phase2<<<1, 128, 0, stream>>>(partials);
    scan_phase3<<<NBLK, SCAN_B, 0, stream>>>(cursor, partials, off);
    init_bcur<<<1, 256, 0, stream>>>(off, bcur);
    bin_edges<<<(NE + 4095) / 4096, 256, 0, stream>>>(es, ed, ew, bcur, srcw2b, dstb);
    hipMemcpyAsync(cursor, off, (size_t)NN * 4, hipMemcpyDeviceToDevice, stream);
    place_edges<<<(NE + 255) / 256, 256, 0, stream>>>(srcw2b, dstb, cursor, edges2);

    // ---- layer 1 ----
    gemm1_tile<<<gemmGrid, 256, 0, stream>>>(x, W1, ws0);
    spmm_csr<<<NN / 4, 256, 0, stream>>>(ws0, off, edges2, b1, h1);

    // ---- layer 2 ----
    gemm2_tile<<<gemmGrid, 256, 0, stream>>>(h1, W2, ws0);
    spmm_csr<<<NN / 4, 256, 0, stream>>>(ws0, off, edges2, b2, h2);

    // ---- head ----
    head_kernel<<<NN / 4, 256, 0, stream>>>(h2, Wl, bl, logits, logp);
}

// Round 6
// 472.362 us; speedup vs baseline: 2.2174x; 1.1752x over previous
//
#include <hip/hip_runtime.h>
#include <math.h>

#define NN 100000
#define NE 1600000
#define SCAN_B 1024
#define NBLK ((NN + SCAN_B - 1) / SCAN_B)   // 98
#define BSHIFT 9
#define NBUCK ((NN + (1 << BSHIFT) - 1) >> BSHIFT)   // 196
#define HROWS 128

// ============ GEMM1: x[N,128] @ W1[128,64] -> out[N,64] ============
__global__ __launch_bounds__(256) void gemm1_tile(const float* __restrict__ x,
                                                  const float* __restrict__ W,
                                                  float* __restrict__ out) {
    __shared__ float Wt[64 * 132];     // 33792 B
    __shared__ float Xs[64 * 68];      // 17408 B   (total 50 KB -> 3 blocks/CU)
    const int tid = threadIdx.x;
    const int row0 = blockIdx.x * 64;
    for (int i = tid; i < 128 * 64; i += 256) {
        const int k = i >> 6, c = i & 63;
        Wt[c * 132 + k] = W[i];
    }
    const int tc = tid & 15;
    const int tr = tid >> 4;
    float acc[4][4] = {};
    const float* wb = &Wt[(tc * 4) * 132];
    for (int kh = 0; kh < 2; ++kh) {
        __syncthreads();
        for (int i = tid; i < 64 * 16; i += 256) {
            const int r = i >> 4, kq = i & 15;
            const int row = row0 + r;
            float4 v = make_float4(0.f, 0.f, 0.f, 0.f);
            if (row < NN) v = *(const float4*)(x + (size_t)row * 128 + kh * 64 + kq * 4);
            *(float4*)(&Xs[r * 68 + kq * 4]) = v;
        }
        __syncthreads();
        const float* xb = &Xs[(tr * 4) * 68];
        for (int k = 0; k < 64; k += 4) {
            float4 xv[4], wv[4];
#pragma unroll
            for (int r = 0; r < 4; ++r) xv[r] = *(const float4*)(xb + r * 68 + k);
#pragma unroll
            for (int c = 0; c < 4; ++c) wv[c] = *(const float4*)(wb + c * 132 + kh * 64 + k);
#pragma unroll
            for (int r = 0; r < 4; ++r)
#pragma unroll
                for (int c = 0; c < 4; ++c) {
                    acc[r][c] = fmaf(xv[r].x, wv[c].x, acc[r][c]);
                    acc[r][c] = fmaf(xv[r].y, wv[c].y, acc[r][c]);
                    acc[r][c] = fmaf(xv[r].z, wv[c].z, acc[r][c]);
                    acc[r][c] = fmaf(xv[r].w, wv[c].w, acc[r][c]);
                }
        }
    }
#pragma unroll
    for (int r = 0; r < 4; ++r) {
        const int row = row0 + tr * 4 + r;
        if (row < NN) {
            const float4 v = make_float4(acc[r][0], acc[r][1], acc[r][2], acc[r][3]);
            *(float4*)(out + (size_t)row * 64 + tc * 4) = v;
        }
    }
}

// ============ GEMM2: h[N,64] @ W2[64,64] -> out[N,64] ============
__global__ __launch_bounds__(256) void gemm2_tile(const float* __restrict__ h,
                                                  const float* __restrict__ W,
                                                  float* __restrict__ out) {
    __shared__ float Wt[64 * 68];
    __shared__ float Xs[64 * 68];
    const int tid = threadIdx.x;
    const int row0 = blockIdx.x * 64;
    for (int i = tid; i < 64 * 64; i += 256) {
        const int k = i >> 6, c = i & 63;
        Wt[c * 68 + k] = W[i];
    }
    for (int i = tid; i < 64 * 16; i += 256) {
        const int r = i >> 4, kq = i & 15;
        const int row = row0 + r;
        float4 v = make_float4(0.f, 0.f, 0.f, 0.f);
        if (row < NN) v = *(const float4*)(h + (size_t)row * 64 + kq * 4);
        *(float4*)(&Xs[r * 68 + kq * 4]) = v;
    }
    __syncthreads();
    const int tc = tid & 15;
    const int tr = tid >> 4;
    float acc[4][4] = {};
    const float* xb = &Xs[(tr * 4) * 68];
    const float* wb = &Wt[(tc * 4) * 68];
    for (int k = 0; k < 64; k += 4) {
        float4 xv[4], wv[4];
#pragma unroll
        for (int r = 0; r < 4; ++r) xv[r] = *(const float4*)(xb + r * 68 + k);
#pragma unroll
        for (int c = 0; c < 4; ++c) wv[c] = *(const float4*)(wb + c * 68 + k);
#pragma unroll
        for (int r = 0; r < 4; ++r)
#pragma unroll
            for (int c = 0; c < 4; ++c) {
                acc[r][c] = fmaf(xv[r].x, wv[c].x, acc[r][c]);
                acc[r][c] = fmaf(xv[r].y, wv[c].y, acc[r][c]);
                acc[r][c] = fmaf(xv[r].z, wv[c].z, acc[r][c]);
                acc[r][c] = fmaf(xv[r].w, wv[c].w, acc[r][c]);
            }
    }
#pragma unroll
    for (int r = 0; r < 4; ++r) {
        const int row = row0 + tr * 4 + r;
        if (row < NN) {
            const float4 v = make_float4(acc[r][0], acc[r][1], acc[r][2], acc[r][3]);
            *(float4*)(out + (size_t)row * 64 + tc * 4) = v;
        }
    }
}

// ---------------- CSR build: histogram of destinations ----------------
__global__ void hist_dst(const int* __restrict__ ed, int* __restrict__ counts) {
    const int e = blockIdx.x * blockDim.x + threadIdx.x;
    atomicAdd(&counts[ed[e]], 1);
}

// ---------------- hierarchical scan: phase 1 — per-block reduce ----------------
__global__ void scan_phase1(const int* __restrict__ counts, int* __restrict__ partials) {
    const int idx = blockIdx.x * SCAN_B + threadIdx.x;
    int v = (idx < NN) ? counts[idx] : 0;
    for (int off = 32; off; off >>= 1) v += __shfl_xor(v, off, 64);
    __shared__ int wsum[16];
    if ((threadIdx.x & 63) == 0) wsum[threadIdx.x >> 6] = v;
    __syncthreads();
    if (threadIdx.x < 16) {
        int s = wsum[threadIdx.x];
        for (int off = 8; off; off >>= 1) s += __shfl_xor(s, off, 16);
        if (threadIdx.x == 0) partials[blockIdx.x] = s;
    }
}

// ---------------- phase 2 — exclusive scan of the 98 partials ----------------
__global__ void scan_phase2(int* __restrict__ partials) {
    __shared__ int p[128];
    const int t = threadIdx.x;
    const int v = (t < NBLK) ? partials[t] : 0;
    p[t] = v;
    __syncthreads();
    for (int d = 1; d < 128; d <<= 1) {
        const int u = (t >= d) ? p[t - d] : 0;
        __syncthreads();
        p[t] += u;
        __syncthreads();
    }
    if (t < NBLK) partials[t] = p[t] - v;
}

// ---------------- phase 3 — block-local exclusive scan + block offset ----------------
__global__ void scan_phase3(const int* __restrict__ counts, const int* __restrict__ partials,
                            int* __restrict__ off) {
    const int b = blockIdx.x;
    const int t = threadIdx.x;
    const int idx = b * SCAN_B + t;
    const int lane = t & 63;
    const int w = t >> 6;
    const int v = (idx < NN) ? counts[idx] : 0;
    int s = v;
    for (int d = 1; d < 64; d <<= 1) {
        const int u = __shfl_up(s, d, 64);
        if (lane >= d) s += u;
    }
    __shared__ int wsum[16];
    if (lane == 63) wsum[w] = s;
    __syncthreads();
    if (t < 16) {
        int ws2 = wsum[t];
        for (int d = 1; d < 16; d <<= 1) {
            const int u = __shfl_up(ws2, d, 16);
            if (t >= d) ws2 += u;
        }
        wsum[t] = ws2;
    }
    __syncthreads();
    const int waveoff = (w == 0) ? 0 : wsum[w - 1];
    if (idx < NN) off[idx] = s - v + waveoff + partials[b];
    if (idx == 0) off[NN] = NE;
}

// ---------------- init coarse-bucket cursors from off ----------------
__global__ void init_bcur(const int* __restrict__ off, int* __restrict__ bcur) {
    const int b = threadIdx.x;
    if (b < NBUCK) bcur[b] = off[b << BSHIFT];
}

// ---------------- pass 1: bin edges into 512-node buckets ----------------
__global__ __launch_bounds__(256) void bin_edges(const int* __restrict__ es,
                                                 const int* __restrict__ ed,
                                                 const float* __restrict__ ew,
                                                 int* __restrict__ bcur,
                                                 int2* __restrict__ srcw2b,
                                                 int* __restrict__ dstb) {
    __shared__ int hist[NBUCK];
    __shared__ int base[NBUCK];
    const int tid = threadIdx.x;
    const int e0 = blockIdx.x * 4096;
    for (int i = tid; i < NBUCK; i += 256) hist[i] = 0;
    __syncthreads();
    int d[16];
#pragma unroll
    for (int j = 0; j < 16; ++j) {
        const int e = e0 + j * 256 + tid;
        d[j] = (e < NE) ? ed[e] : -1;
        if (d[j] >= 0) atomicAdd(&hist[d[j] >> BSHIFT], 1);
    }
    __syncthreads();
    for (int i = tid; i < NBUCK; i += 256) base[i] = atomicAdd(&bcur[i], hist[i]);
    __syncthreads();
    for (int i = tid; i < NBUCK; i += 256) hist[i] = 0;
    __syncthreads();
#pragma unroll
    for (int j = 0; j < 16; ++j) {
        const int e = e0 + j * 256 + tid;
        if (d[j] >= 0) {
            const int b = d[j] >> BSHIFT;
            const int l = atomicAdd(&hist[b], 1);
            const int p = base[b] + l;
            srcw2b[p] = make_int2(es[e], __float_as_int(ew[e]));
            dstb[p] = d[j];
        }
    }
}

// ---------------- pass 2: place within L2-resident bucket windows ----------------
__global__ void place_edges(const int2* __restrict__ srcw2b, const int* __restrict__ dstb,
                            int* __restrict__ cursor, int2* __restrict__ edges2) {
    const int e = blockIdx.x * blockDim.x + threadIdx.x;
    if (e < NE) {
        const int dd = dstb[e];
        const int p = atomicAdd(&cursor[dd], 1);
        edges2[p] = srcw2b[e];
    }
}

// ---------------- CSR SpMM + bias + relu: one wave per dest node ----------------
__global__ __launch_bounds__(256) void spmm_csr(const float* __restrict__ feat,
                                                const int* __restrict__ off,
                                                const int2* __restrict__ edges2,
                                                const float* __restrict__ b,
                                                float* __restrict__ out) {
    const int w = threadIdx.x >> 6;
    const int lane = threadIdx.x & 63;
    const int n = blockIdx.x * 4 + w;
    const int beg = off[n];
    const int end = off[n + 1];
    float acc = 0.f;
    int i = beg;
    for (; i + 3 < end; i += 4) {
        const int2 e0 = edges2[i];
        const int2 e1 = edges2[i + 1];
        const int2 e2 = edges2[i + 2];
        const int2 e3 = edges2[i + 3];
        const float f0 = feat[(size_t)e0.x * 64 + lane];
        const float f1 = feat[(size_t)e1.x * 64 + lane];
        const float f2 = feat[(size_t)e2.x * 64 + lane];
        const float f3 = feat[(size_t)e3.x * 64 + lane];
        acc = fmaf(f0, __int_as_float(e0.y), acc);
        acc = fmaf(f1, __int_as_float(e1.y), acc);
        acc = fmaf(f2, __int_as_float(e2.y), acc);
        acc = fmaf(f3, __int_as_float(e3.y), acc);
    }
    for (; i < end; ++i) {
        const int2 e = edges2[i];
        acc = fmaf(feat[(size_t)e.x * 64 + lane], __int_as_float(e.y), acc);
    }
    const float v = acc + b[lane];
    out[(size_t)n * 64 + lane] = v > 0.f ? v : 0.f;
}

// ============ head: 128 rows x 40 cols per block, register-tiled ============
// thread t: tcol = t&3 (10 cols), trow = t>>2; computes rows {trow, trow+64}.
__global__ __launch_bounds__(256) void head_tile(const float* __restrict__ h2,
                                                 const float* __restrict__ Wl,
                                                 const float* __restrict__ bl,
                                                 float* __restrict__ logits,
                                                 float* __restrict__ logp) {
    __shared__ float Wt[40 * 68];      // 10880 B  (Wt[c][k], pad 68)
    __shared__ float Xs[HROWS * 68];   // 34816 B  (total ~46 KB -> 3 blocks/CU)
    __shared__ float bs[40];
    const int tid = threadIdx.x;
    const int row0 = blockIdx.x * HROWS;
    for (int i = tid; i < 64 * 40; i += 256) {
        const int k = i / 40, c = i - k * 40;
        Wt[c * 68 + k] = Wl[i];
    }
    if (tid < 40) bs[tid] = bl[tid];
    for (int i = tid; i < HROWS * 16; i += 256) {
        const int r = i >> 4, kq = i & 15;
        const int row = row0 + r;
        float4 v = make_float4(0.f, 0.f, 0.f, 0.f);
        if (row < NN) v = *(const float4*)(h2 + (size_t)row * 64 + kq * 4);
        *(float4*)(&Xs[r * 68 + kq * 4]) = v;
    }
    __syncthreads();
    const int tcol = tid & 3;          // 4 col groups x 10 cols
    const int trow = tid >> 2;         // rows trow and trow+64
    float acc[2][10] = {};
    const float* xb0 = &Xs[trow * 68];
    const float* xb1 = &Xs[(trow + 64) * 68];
    const float* wb = &Wt[(tcol * 10) * 68];
    for (int k = 0; k < 64; k += 4) {
        const float4 x0 = *(const float4*)(xb0 + k);
        const float4 x1 = *(const float4*)(xb1 + k);
#pragma unroll
        for (int c = 0; c < 10; ++c) {
            const float4 wv = *(const float4*)(wb + c * 68 + k);
            acc[0][c] = fmaf(x0.x, wv.x, acc[0][c]);
            acc[0][c] = fmaf(x0.y, wv.y, acc[0][c]);
            acc[0][c] = fmaf(x0.z, wv.z, acc[0][c]);
            acc[0][c] = fmaf(x0.w, wv.w, acc[0][c]);
            acc[1][c] = fmaf(x1.x, wv.x, acc[1][c]);
            acc[1][c] = fmaf(x1.y, wv.y, acc[1][c]);
            acc[1][c] = fmaf(x1.z, wv.z, acc[1][c]);
            acc[1][c] = fmaf(x1.w, wv.w, acc[1][c]);
        }
    }
    float bv[10];
#pragma unroll
    for (int c = 0; c < 10; ++c) bv[c] = bs[tcol * 10 + c];
#pragma unroll
    for (int r = 0; r < 2; ++r) {
        const int row = row0 + trow + r * 64;
#pragma unroll
        for (int c = 0; c < 10; ++c) acc[r][c] += bv[c];
        // quad-wide log-softmax (4 lanes x 10 cols = 40)
        float m = acc[r][0];
#pragma unroll
        for (int c = 1; c < 10; ++c) m = fmaxf(m, acc[r][c]);
        m = fmaxf(m, __shfl_xor(m, 1, 64));
        m = fmaxf(m, __shfl_xor(m, 2, 64));
        float s = 0.f;
#pragma unroll
        for (int c = 0; c < 10; ++c) s += expf(acc[r][c] - m);
        s += __shfl_xor(s, 1, 64);
        s += __shfl_xor(s, 2, 64);
        const float lse = logf(s) + m;
        if (row < NN) {
            float* lg = logits + (size_t)row * 40 + tcol * 10;
            float* lp = logp   + (size_t)row * 40 + tcol * 10;
#pragma unroll
            for (int c = 0; c < 10; c += 2) {
                *(float2*)(lg + c) = make_float2(acc[r][c], acc[r][c + 1]);
                *(float2*)(lp + c) = make_float2(acc[r][c] - lse, acc[r][c + 1] - lse);
            }
        }
    }
}

extern "C" void kernel_launch(void* const* d_in, const int* in_sizes, int n_in,
                              void* d_out, int out_size, void* d_ws, size_t ws_size,
                              hipStream_t stream) {
    const float* x  = (const float*)d_in[0];
    const int*   es = (const int*)  d_in[1];
    const int*   ed = (const int*)  d_in[2];
    const float* ew = (const float*)d_in[3];
    const float* W1 = (const float*)d_in[4];
    const float* b1 = (const float*)d_in[5];
    const float* W2 = (const float*)d_in[6];
    const float* b2 = (const float*)d_in[7];
    const float* Wl = (const float*)d_in[8];
    const float* bl = (const float*)d_in[9];

    float* out    = (float*)d_out;
    float* logp   = out;                          // [N,40]
    float* h1     = logp + (size_t)NN * 40;       // [N,64]
    float* h2     = h1   + (size_t)NN * 64;       // [N,64]
    float* logits = h2   + (size_t)NN * 64;       // [N,40]

    // workspace layout
    char* wsb = (char*)d_ws;
    float* ws0     = (float*)wsb;                               // [N,64] 25.6 MB (GEMM out)
    int2*  srcw2b  = (int2*)wsb;                                // binned edges  (overlays ws0)
    int*   dstb    = (int*)(wsb + (size_t)NE * 8);              // binned dsts   (overlays ws0)
    int2*  edges2  = (int2*)(wsb + (size_t)NN * 64 * 4);        // [E] 12.8 MB
    int*   off     = (int*)((char*)edges2 + (size_t)NE * 8);    // [N+1]
    int*   cursor  = off + (NN + 1);                            // [N]
    int*   partials = cursor + NN;                              // [NBLK]
    int*   bcur    = partials + NBLK;                           // [NBUCK]

    const int gemmGrid = (NN + 63) / 64;

    // ---- build dest-sorted CSR (once, reused by both layers) ----
    hipMemsetAsync(cursor, 0, (size_t)NN * 4, stream);
    hist_dst<<<NE / 256, 256, 0, stream>>>(ed, cursor);
    scan_phase1<<<NBLK, SCAN_B, 0, stream>>>(cursor, partials);
    scan_phase2<<<1, 128, 0, stream>>>(partials);
    scan_phase3<<<NBLK, SCAN_B, 0, stream>>>(cursor, partials, off);
    init_bcur<<<1, 256, 0, stream>>>(off, bcur);
    bin_edges<<<(NE + 4095) / 4096, 256, 0, stream>>>(es, ed, ew, bcur, srcw2b, dstb);
    hipMemcpyAsync(cursor, off, (size_t)NN * 4, hipMemcpyDeviceToDevice, stream);
    place_edges<<<(NE + 255) / 256, 256, 0, stream>>>(srcw2b, dstb, cursor, edges2);

    // ---- layer 1 ----
    gemm1_tile<<<gemmGrid, 256, 0, stream>>>(x, W1, ws0);
    spmm_csr<<<NN / 4, 256, 0, stream>>>(ws0, off, edges2, b1, h1);

    // ---- layer 2 ----
    gemm2_tile<<<gemmGrid, 256, 0, stream>>>(h1, W2, ws0);
    spmm_csr<<<NN / 4, 256, 0, stream>>>(ws0, off, edges2, b2, h2);

    // ---- head ----
    head_tile<<<(NN + HROWS - 1) / HROWS, 256, 0, stream>>>(h2, Wl, bl, logits, logp);
}

// Round 7
// 420.649 us; speedup vs baseline: 2.4900x; 1.1229x over previous
//
#include <hip/hip_runtime.h>
#include <math.h>

#define NN 100000
#define NE 1600000
#define SCAN_B 1024
#define NBLK ((NN + SCAN_B - 1) / SCAN_B)   // 98
#define BSHIFT 9
#define NBUCK ((NN + (1 << BSHIFT) - 1) >> BSHIFT)   // 196
#define HROWS 128

// ============ GEMM1: x[N,128] @ W1[128,64] -> out[N,64] ============
// 64-row tile, 256 threads, thread = 4 rows x 4 INTERLEAVED cols {tc,tc+16,tc+32,tc+48}.
// Lane stride on Wt reads = 132 floats = 4 banks -> 2-way (free). Staging writes stride-1.
__global__ __launch_bounds__(256, 3) void gemm1_tile(const float* __restrict__ x,
                                                     const float* __restrict__ W,
                                                     float* __restrict__ out) {
    __shared__ float Wt[64 * 132];     // 33792 B
    __shared__ float Xs[64 * 68];      // 17408 B
    const int tid = threadIdx.x;
    const int row0 = blockIdx.x * 64;
    // stage W transposed: lanes walk k (stride-1 LDS writes); W reads L2-hot
    for (int i = tid; i < 64 * 128; i += 256) {
        const int c = i >> 7, k = i & 127;
        Wt[c * 132 + k] = W[k * 64 + c];
    }
    const int tc = tid & 15;
    const int tr = tid >> 4;
    float acc[4][4] = {};
    const float* wb = &Wt[tc * 132];
    for (int kh = 0; kh < 2; ++kh) {
        __syncthreads();
        for (int i = tid; i < 64 * 16; i += 256) {
            const int r = i >> 4, kq = i & 15;
            const int row = row0 + r;
            float4 v = make_float4(0.f, 0.f, 0.f, 0.f);
            if (row < NN) v = *(const float4*)(x + (size_t)row * 128 + kh * 64 + kq * 4);
            *(float4*)(&Xs[r * 68 + kq * 4]) = v;
        }
        __syncthreads();
        const float* xb = &Xs[(tr * 4) * 68];
#pragma unroll 2
        for (int k = 0; k < 64; k += 4) {
            float4 xv[4], wv[4];
#pragma unroll
            for (int r = 0; r < 4; ++r) xv[r] = *(const float4*)(xb + r * 68 + k);
#pragma unroll
            for (int c = 0; c < 4; ++c) wv[c] = *(const float4*)(wb + c * (16 * 132) + kh * 64 + k);
#pragma unroll
            for (int r = 0; r < 4; ++r)
#pragma unroll
                for (int c = 0; c < 4; ++c) {
                    acc[r][c] = fmaf(xv[r].x, wv[c].x, acc[r][c]);
                    acc[r][c] = fmaf(xv[r].y, wv[c].y, acc[r][c]);
                    acc[r][c] = fmaf(xv[r].z, wv[c].z, acc[r][c]);
                    acc[r][c] = fmaf(xv[r].w, wv[c].w, acc[r][c]);
                }
        }
    }
#pragma unroll
    for (int r = 0; r < 4; ++r) {
        const int row = row0 + tr * 4 + r;
        if (row < NN) {
#pragma unroll
            for (int c = 0; c < 4; ++c) out[(size_t)row * 64 + tc + c * 16] = acc[r][c];
        }
    }
}

// ============ GEMM2: h[N,64] @ W2[64,64] -> out[N,64] ============
__global__ __launch_bounds__(256, 3) void gemm2_tile(const float* __restrict__ h,
                                                     const float* __restrict__ W,
                                                     float* __restrict__ out) {
    __shared__ float Wt[64 * 68];
    __shared__ float Xs[64 * 68];
    const int tid = threadIdx.x;
    const int row0 = blockIdx.x * 64;
    for (int i = tid; i < 64 * 64; i += 256) {
        const int c = i >> 6, k = i & 63;
        Wt[c * 68 + k] = W[k * 64 + c];
    }
    for (int i = tid; i < 64 * 16; i += 256) {
        const int r = i >> 4, kq = i & 15;
        const int row = row0 + r;
        float4 v = make_float4(0.f, 0.f, 0.f, 0.f);
        if (row < NN) v = *(const float4*)(h + (size_t)row * 64 + kq * 4);
        *(float4*)(&Xs[r * 68 + kq * 4]) = v;
    }
    __syncthreads();
    const int tc = tid & 15;
    const int tr = tid >> 4;
    float acc[4][4] = {};
    const float* xb = &Xs[(tr * 4) * 68];
    const float* wb = &Wt[tc * 68];
#pragma unroll 2
    for (int k = 0; k < 64; k += 4) {
        float4 xv[4], wv[4];
#pragma unroll
        for (int r = 0; r < 4; ++r) xv[r] = *(const float4*)(xb + r * 68 + k);
#pragma unroll
        for (int c = 0; c < 4; ++c) wv[c] = *(const float4*)(wb + c * (16 * 68) + k);
#pragma unroll
        for (int r = 0; r < 4; ++r)
#pragma unroll
            for (int c = 0; c < 4; ++c) {
                acc[r][c] = fmaf(xv[r].x, wv[c].x, acc[r][c]);
                acc[r][c] = fmaf(xv[r].y, wv[c].y, acc[r][c]);
                acc[r][c] = fmaf(xv[r].z, wv[c].z, acc[r][c]);
                acc[r][c] = fmaf(xv[r].w, wv[c].w, acc[r][c]);
            }
    }
#pragma unroll
    for (int r = 0; r < 4; ++r) {
        const int row = row0 + tr * 4 + r;
        if (row < NN) {
#pragma unroll
            for (int c = 0; c < 4; ++c) out[(size_t)row * 64 + tc + c * 16] = acc[r][c];
        }
    }
}

// ---------------- CSR build: histogram of destinations ----------------
__global__ void hist_dst(const int* __restrict__ ed, int* __restrict__ counts) {
    const int e = blockIdx.x * blockDim.x + threadIdx.x;
    atomicAdd(&counts[ed[e]], 1);
}

// ---------------- hierarchical scan: phase 1 — per-block reduce ----------------
__global__ void scan_phase1(const int* __restrict__ counts, int* __restrict__ partials) {
    const int idx = blockIdx.x * SCAN_B + threadIdx.x;
    int v = (idx < NN) ? counts[idx] : 0;
    for (int off = 32; off; off >>= 1) v += __shfl_xor(v, off, 64);
    __shared__ int wsum[16];
    if ((threadIdx.x & 63) == 0) wsum[threadIdx.x >> 6] = v;
    __syncthreads();
    if (threadIdx.x < 16) {
        int s = wsum[threadIdx.x];
        for (int off = 8; off; off >>= 1) s += __shfl_xor(s, off, 16);
        if (threadIdx.x == 0) partials[blockIdx.x] = s;
    }
}

// ---------------- phase 2 — exclusive scan of the 98 partials ----------------
__global__ void scan_phase2(int* __restrict__ partials) {
    __shared__ int p[128];
    const int t = threadIdx.x;
    const int v = (t < NBLK) ? partials[t] : 0;
    p[t] = v;
    __syncthreads();
    for (int d = 1; d < 128; d <<= 1) {
        const int u = (t >= d) ? p[t - d] : 0;
        __syncthreads();
        p[t] += u;
        __syncthreads();
    }
    if (t < NBLK) partials[t] = p[t] - v;
}

// ---------------- phase 3 — block-local exclusive scan + block offset ----------------
__global__ void scan_phase3(const int* __restrict__ counts, const int* __restrict__ partials,
                            int* __restrict__ off) {
    const int b = blockIdx.x;
    const int t = threadIdx.x;
    const int idx = b * SCAN_B + t;
    const int lane = t & 63;
    const int w = t >> 6;
    const int v = (idx < NN) ? counts[idx] : 0;
    int s = v;
    for (int d = 1; d < 64; d <<= 1) {
        const int u = __shfl_up(s, d, 64);
        if (lane >= d) s += u;
    }
    __shared__ int wsum[16];
    if (lane == 63) wsum[w] = s;
    __syncthreads();
    if (t < 16) {
        int ws2 = wsum[t];
        for (int d = 1; d < 16; d <<= 1) {
            const int u = __shfl_up(ws2, d, 16);
            if (t >= d) ws2 += u;
        }
        wsum[t] = ws2;
    }
    __syncthreads();
    const int waveoff = (w == 0) ? 0 : wsum[w - 1];
    if (idx < NN) off[idx] = s - v + waveoff + partials[b];
    if (idx == 0) off[NN] = NE;
}

// ---------------- init coarse-bucket cursors from off ----------------
__global__ void init_bcur(const int* __restrict__ off, int* __restrict__ bcur) {
    const int b = threadIdx.x;
    if (b < NBUCK) bcur[b] = off[b << BSHIFT];
}

// ---------------- pass 1: bin edges into 512-node buckets ----------------
__global__ __launch_bounds__(256) void bin_edges(const int* __restrict__ es,
                                                 const int* __restrict__ ed,
                                                 const float* __restrict__ ew,
                                                 int* __restrict__ bcur,
                                                 int2* __restrict__ srcw2b,
                                                 int* __restrict__ dstb) {
    __shared__ int hist[NBUCK];
    __shared__ int base[NBUCK];
    const int tid = threadIdx.x;
    const int e0 = blockIdx.x * 4096;
    for (int i = tid; i < NBUCK; i += 256) hist[i] = 0;
    __syncthreads();
    int d[16];
#pragma unroll
    for (int j = 0; j < 16; ++j) {
        const int e = e0 + j * 256 + tid;
        d[j] = (e < NE) ? ed[e] : -1;
        if (d[j] >= 0) atomicAdd(&hist[d[j] >> BSHIFT], 1);
    }
    __syncthreads();
    for (int i = tid; i < NBUCK; i += 256) base[i] = atomicAdd(&bcur[i], hist[i]);
    __syncthreads();
    for (int i = tid; i < NBUCK; i += 256) hist[i] = 0;
    __syncthreads();
#pragma unroll
    for (int j = 0; j < 16; ++j) {
        const int e = e0 + j * 256 + tid;
        if (d[j] >= 0) {
            const int b = d[j] >> BSHIFT;
            const int l = atomicAdd(&hist[b], 1);
            const int p = base[b] + l;
            srcw2b[p] = make_int2(es[e], __float_as_int(ew[e]));
            dstb[p] = d[j];
        }
    }
}

// ---------------- pass 2: place within L2-resident bucket windows ----------------
__global__ void place_edges(const int2* __restrict__ srcw2b, const int* __restrict__ dstb,
                            int* __restrict__ cursor, int2* __restrict__ edges2) {
    const int e = blockIdx.x * blockDim.x + threadIdx.x;
    if (e < NE) {
        const int dd = dstb[e];
        const int p = atomicAdd(&cursor[dd], 1);
        edges2[p] = srcw2b[e];
    }
}

// ---------------- CSR SpMM + bias + relu: one wave per dest node ----------------
__global__ __launch_bounds__(256) void spmm_csr(const float* __restrict__ feat,
                                                const int* __restrict__ off,
                                                const int2* __restrict__ edges2,
                                                const float* __restrict__ b,
                                                float* __restrict__ out) {
    const int w = threadIdx.x >> 6;
    const int lane = threadIdx.x & 63;
    const int n = blockIdx.x * 4 + w;
    const int beg = off[n];
    const int end = off[n + 1];
    float acc = 0.f;
    int i = beg;
    for (; i + 3 < end; i += 4) {
        const int2 e0 = edges2[i];
        const int2 e1 = edges2[i + 1];
        const int2 e2 = edges2[i + 2];
        const int2 e3 = edges2[i + 3];
        const float f0 = feat[(size_t)e0.x * 64 + lane];
        const float f1 = feat[(size_t)e1.x * 64 + lane];
        const float f2 = feat[(size_t)e2.x * 64 + lane];
        const float f3 = feat[(size_t)e3.x * 64 + lane];
        acc = fmaf(f0, __int_as_float(e0.y), acc);
        acc = fmaf(f1, __int_as_float(e1.y), acc);
        acc = fmaf(f2, __int_as_float(e2.y), acc);
        acc = fmaf(f3, __int_as_float(e3.y), acc);
    }
    for (; i < end; ++i) {
        const int2 e = edges2[i];
        acc = fmaf(feat[(size_t)e.x * 64 + lane], __int_as_float(e.y), acc);
    }
    const float v = acc + b[lane];
    out[(size_t)n * 64 + lane] = v > 0.f ? v : 0.f;
}

// ============ head: 128 rows x 40 cols per block, register-tiled ============
__global__ __launch_bounds__(256) void head_tile(const float* __restrict__ h2,
                                                 const float* __restrict__ Wl,
                                                 const float* __restrict__ bl,
                                                 float* __restrict__ logits,
                                                 float* __restrict__ logp) {
    __shared__ float Wt[40 * 68];      // 10880 B
    __shared__ float Xs[HROWS * 68];   // 34816 B
    __shared__ float bs[40];
    const int tid = threadIdx.x;
    const int row0 = blockIdx.x * HROWS;
    for (int i = tid; i < 64 * 40; i += 256) {
        const int k = i / 40, c = i - k * 40;
        Wt[c * 68 + k] = Wl[i];
    }
    if (tid < 40) bs[tid] = bl[tid];
    for (int i = tid; i < HROWS * 16; i += 256) {
        const int r = i >> 4, kq = i & 15;
        const int row = row0 + r;
        float4 v = make_float4(0.f, 0.f, 0.f, 0.f);
        if (row < NN) v = *(const float4*)(h2 + (size_t)row * 64 + kq * 4);
        *(float4*)(&Xs[r * 68 + kq * 4]) = v;
    }
    __syncthreads();
    const int tcol = tid & 3;
    const int trow = tid >> 2;
    float acc[2][10] = {};
    const float* xb0 = &Xs[trow * 68];
    const float* xb1 = &Xs[(trow + 64) * 68];
    const float* wb = &Wt[(tcol * 10) * 68];
    for (int k = 0; k < 64; k += 4) {
        const float4 x0 = *(const float4*)(xb0 + k);
        const float4 x1 = *(const float4*)(xb1 + k);
#pragma unroll
        for (int c = 0; c < 10; ++c) {
            const float4 wv = *(const float4*)(wb + c * 68 + k);
            acc[0][c] = fmaf(x0.x, wv.x, acc[0][c]);
            acc[0][c] = fmaf(x0.y, wv.y, acc[0][c]);
            acc[0][c] = fmaf(x0.z, wv.z, acc[0][c]);
            acc[0][c] = fmaf(x0.w, wv.w, acc[0][c]);
            acc[1][c] = fmaf(x1.x, wv.x, acc[1][c]);
            acc[1][c] = fmaf(x1.y, wv.y, acc[1][c]);
            acc[1][c] = fmaf(x1.z, wv.z, acc[1][c]);
            acc[1][c] = fmaf(x1.w, wv.w, acc[1][c]);
        }
    }
    float bv[10];
#pragma unroll
    for (int c = 0; c < 10; ++c) bv[c] = bs[tcol * 10 + c];
#pragma unroll
    for (int r = 0; r < 2; ++r) {
        const int row = row0 + trow + r * 64;
#pragma unroll
        for (int c = 0; c < 10; ++c) acc[r][c] += bv[c];
        float m = acc[r][0];
#pragma unroll
        for (int c = 1; c < 10; ++c) m = fmaxf(m, acc[r][c]);
        m = fmaxf(m, __shfl_xor(m, 1, 64));
        m = fmaxf(m, __shfl_xor(m, 2, 64));
        float s = 0.f;
#pragma unroll
        for (int c = 0; c < 10; ++c) s += expf(acc[r][c] - m);
        s += __shfl_xor(s, 1, 64);
        s += __shfl_xor(s, 2, 64);
        const float lse = logf(s) + m;
        if (row < NN) {
            float* lg = logits + (size_t)row * 40 + tcol * 10;
            float* lp = logp   + (size_t)row * 40 + tcol * 10;
#pragma unroll
            for (int c = 0; c < 10; c += 2) {
                *(float2*)(lg + c) = make_float2(acc[r][c], acc[r][c + 1]);
                *(float2*)(lp + c) = make_float2(acc[r][c] - lse, acc[r][c + 1] - lse);
            }
        }
    }
}

extern "C" void kernel_launch(void* const* d_in, const int* in_sizes, int n_in,
                              void* d_out, int out_size, void* d_ws, size_t ws_size,
                              hipStream_t stream) {
    const float* x  = (const float*)d_in[0];
    const int*   es = (const int*)  d_in[1];
    const int*   ed = (const int*)  d_in[2];
    const float* ew = (const float*)d_in[3];
    const float* W1 = (const float*)d_in[4];
    const float* b1 = (const float*)d_in[5];
    const float* W2 = (const float*)d_in[6];
    const float* b2 = (const float*)d_in[7];
    const float* Wl = (const float*)d_in[8];
    const float* bl = (const float*)d_in[9];

    float* out    = (float*)d_out;
    float* logp   = out;                          // [N,40]
    float* h1     = logp + (size_t)NN * 40;       // [N,64]
    float* h2     = h1   + (size_t)NN * 64;       // [N,64]
    float* logits = h2   + (size_t)NN * 64;       // [N,40]

    // workspace layout
    char* wsb = (char*)d_ws;
    float* ws0     = (float*)wsb;                               // [N,64] 25.6 MB (GEMM out)
    int2*  srcw2b  = (int2*)wsb;                                // binned edges  (overlays ws0)
    int*   dstb    = (int*)(wsb + (size_t)NE * 8);              // binned dsts   (overlays ws0)
    int2*  edges2  = (int2*)(wsb + (size_t)NN * 64 * 4);        // [E] 12.8 MB
    int*   off     = (int*)((char*)edges2 + (size_t)NE * 8);    // [N+1]
    int*   cursor  = off + (NN + 1);                            // [N]
    int*   partials = cursor + NN;                              // [NBLK]
    int*   bcur    = partials + NBLK;                           // [NBUCK]

    const int gemmGrid = (NN + 63) / 64;

    // ---- build dest-sorted CSR (once, reused by both layers) ----
    hipMemsetAsync(cursor, 0, (size_t)NN * 4, stream);
    hist_dst<<<NE / 256, 256, 0, stream>>>(ed, cursor);
    scan_phase1<<<NBLK, SCAN_B, 0, stream>>>(cursor, partials);
    scan_phase2<<<1, 128, 0, stream>>>(partials);
    scan_phase3<<<NBLK, SCAN_B, 0, stream>>>(cursor, partials, off);
    init_bcur<<<1, 256, 0, stream>>>(off, bcur);
    bin_edges<<<(NE + 4095) / 4096, 256, 0, stream>>>(es, ed, ew, bcur, srcw2b, dstb);
    hipMemcpyAsync(cursor, off, (size_t)NN * 4, hipMemcpyDeviceToDevice, stream);
    place_edges<<<(NE + 255) / 256, 256, 0, stream>>>(srcw2b, dstb, cursor, edges2);

    // ---- layer 1 ----
    gemm1_tile<<<gemmGrid, 256, 0, stream>>>(x, W1, ws0);
    spmm_csr<<<NN / 4, 256, 0, stream>>>(ws0, off, edges2, b1, h1);

    // ---- layer 2 ----
    gemm2_tile<<<gemmGrid, 256, 0, stream>>>(h1, W2, ws0);
    spmm_csr<<<NN / 4, 256, 0, stream>>>(ws0, off, edges2, b2, h2);

    // ---- head ----
    head_tile<<<(NN + HROWS - 1) / HROWS, 256, 0, stream>>>(h2, Wl, bl, logits, logp);
}

// Round 8
// 409.410 us; speedup vs baseline: 2.5583x; 1.0275x over previous
//
#include <hip/hip_runtime.h>
#include <hip/hip_bf16.h>
#include <math.h>

#define NN 100000
#define NE 1600000
#define SCAN_B 1024
#define NBLK ((NN + SCAN_B - 1) / SCAN_B)   // 98
#define BSHIFT 9
#define NBUCK ((NN + (1 << BSHIFT) - 1) >> BSHIFT)   // 196
#define HROWS 128

// ============ GEMM1: x[N,128] @ W1[128,64] -> out_bf16[N,64] ============
// 64-row tile, 256 threads, thread = 4 rows x 4 INTERLEAVED cols {tc,tc+16,tc+32,tc+48}.
__global__ __launch_bounds__(256, 3) void gemm1_tile(const float* __restrict__ x,
                                                     const float* __restrict__ W,
                                                     __hip_bfloat16* __restrict__ out) {
    __shared__ float Wt[64 * 132];     // 33792 B
    __shared__ float Xs[64 * 68];      // 17408 B
    const int tid = threadIdx.x;
    const int row0 = blockIdx.x * 64;
    for (int i = tid; i < 64 * 128; i += 256) {
        const int c = i >> 7, k = i & 127;
        Wt[c * 132 + k] = W[k * 64 + c];
    }
    const int tc = tid & 15;
    const int tr = tid >> 4;
    float acc[4][4] = {};
    const float* wb = &Wt[tc * 132];
    for (int kh = 0; kh < 2; ++kh) {
        __syncthreads();
        for (int i = tid; i < 64 * 16; i += 256) {
            const int r = i >> 4, kq = i & 15;
            const int row = row0 + r;
            float4 v = make_float4(0.f, 0.f, 0.f, 0.f);
            if (row < NN) v = *(const float4*)(x + (size_t)row * 128 + kh * 64 + kq * 4);
            *(float4*)(&Xs[r * 68 + kq * 4]) = v;
        }
        __syncthreads();
        const float* xb = &Xs[(tr * 4) * 68];
#pragma unroll 2
        for (int k = 0; k < 64; k += 4) {
            float4 xv[4], wv[4];
#pragma unroll
            for (int r = 0; r < 4; ++r) xv[r] = *(const float4*)(xb + r * 68 + k);
#pragma unroll
            for (int c = 0; c < 4; ++c) wv[c] = *(const float4*)(wb + c * (16 * 132) + kh * 64 + k);
#pragma unroll
            for (int r = 0; r < 4; ++r)
#pragma unroll
                for (int c = 0; c < 4; ++c) {
                    acc[r][c] = fmaf(xv[r].x, wv[c].x, acc[r][c]);
                    acc[r][c] = fmaf(xv[r].y, wv[c].y, acc[r][c]);
                    acc[r][c] = fmaf(xv[r].z, wv[c].z, acc[r][c]);
                    acc[r][c] = fmaf(xv[r].w, wv[c].w, acc[r][c]);
                }
        }
    }
#pragma unroll
    for (int r = 0; r < 4; ++r) {
        const int row = row0 + tr * 4 + r;
        if (row < NN) {
#pragma unroll
            for (int c = 0; c < 4; ++c)
                out[(size_t)row * 64 + tc + c * 16] = __float2bfloat16(acc[r][c]);
        }
    }
}

// ============ GEMM2: h[N,64] @ W2[64,64] -> out_bf16[N,64] ============
__global__ __launch_bounds__(256, 3) void gemm2_tile(const float* __restrict__ h,
                                                     const float* __restrict__ W,
                                                     __hip_bfloat16* __restrict__ out) {
    __shared__ float Wt[64 * 68];
    __shared__ float Xs[64 * 68];
    const int tid = threadIdx.x;
    const int row0 = blockIdx.x * 64;
    for (int i = tid; i < 64 * 64; i += 256) {
        const int c = i >> 6, k = i & 63;
        Wt[c * 68 + k] = W[k * 64 + c];
    }
    for (int i = tid; i < 64 * 16; i += 256) {
        const int r = i >> 4, kq = i & 15;
        const int row = row0 + r;
        float4 v = make_float4(0.f, 0.f, 0.f, 0.f);
        if (row < NN) v = *(const float4*)(h + (size_t)row * 64 + kq * 4);
        *(float4*)(&Xs[r * 68 + kq * 4]) = v;
    }
    __syncthreads();
    const int tc = tid & 15;
    const int tr = tid >> 4;
    float acc[4][4] = {};
    const float* xb = &Xs[(tr * 4) * 68];
    const float* wb = &Wt[tc * 68];
#pragma unroll 2
    for (int k = 0; k < 64; k += 4) {
        float4 xv[4], wv[4];
#pragma unroll
        for (int r = 0; r < 4; ++r) xv[r] = *(const float4*)(xb + r * 68 + k);
#pragma unroll
        for (int c = 0; c < 4; ++c) wv[c] = *(const float4*)(wb + c * (16 * 68) + k);
#pragma unroll
        for (int r = 0; r < 4; ++r)
#pragma unroll
            for (int c = 0; c < 4; ++c) {
                acc[r][c] = fmaf(xv[r].x, wv[c].x, acc[r][c]);
                acc[r][c] = fmaf(xv[r].y, wv[c].y, acc[r][c]);
                acc[r][c] = fmaf(xv[r].z, wv[c].z, acc[r][c]);
                acc[r][c] = fmaf(xv[r].w, wv[c].w, acc[r][c]);
            }
    }
#pragma unroll
    for (int r = 0; r < 4; ++r) {
        const int row = row0 + tr * 4 + r;
        if (row < NN) {
#pragma unroll
            for (int c = 0; c < 4; ++c)
                out[(size_t)row * 64 + tc + c * 16] = __float2bfloat16(acc[r][c]);
        }
    }
}

// ---------------- CSR build: histogram of destinations ----------------
__global__ void hist_dst(const int* __restrict__ ed, int* __restrict__ counts) {
    const int e = blockIdx.x * blockDim.x + threadIdx.x;
    atomicAdd(&counts[ed[e]], 1);
}

// ---------------- hierarchical scan: phase 1 — per-block reduce ----------------
__global__ void scan_phase1(const int* __restrict__ counts, int* __restrict__ partials) {
    const int idx = blockIdx.x * SCAN_B + threadIdx.x;
    int v = (idx < NN) ? counts[idx] : 0;
    for (int off = 32; off; off >>= 1) v += __shfl_xor(v, off, 64);
    __shared__ int wsum[16];
    if ((threadIdx.x & 63) == 0) wsum[threadIdx.x >> 6] = v;
    __syncthreads();
    if (threadIdx.x < 16) {
        int s = wsum[threadIdx.x];
        for (int off = 8; off; off >>= 1) s += __shfl_xor(s, off, 16);
        if (threadIdx.x == 0) partials[blockIdx.x] = s;
    }
}

// ---------------- phase 2 — exclusive scan of the 98 partials ----------------
__global__ void scan_phase2(int* __restrict__ partials) {
    __shared__ int p[128];
    const int t = threadIdx.x;
    const int v = (t < NBLK) ? partials[t] : 0;
    p[t] = v;
    __syncthreads();
    for (int d = 1; d < 128; d <<= 1) {
        const int u = (t >= d) ? p[t - d] : 0;
        __syncthreads();
        p[t] += u;
        __syncthreads();
    }
    if (t < NBLK) partials[t] = p[t] - v;
}

// ---------------- phase 3 — block-local exclusive scan + block offset ----------------
__global__ void scan_phase3(const int* __restrict__ counts, const int* __restrict__ partials,
                            int* __restrict__ off) {
    const int b = blockIdx.x;
    const int t = threadIdx.x;
    const int idx = b * SCAN_B + t;
    const int lane = t & 63;
    const int w = t >> 6;
    const int v = (idx < NN) ? counts[idx] : 0;
    int s = v;
    for (int d = 1; d < 64; d <<= 1) {
        const int u = __shfl_up(s, d, 64);
        if (lane >= d) s += u;
    }
    __shared__ int wsum[16];
    if (lane == 63) wsum[w] = s;
    __syncthreads();
    if (t < 16) {
        int ws2 = wsum[t];
        for (int d = 1; d < 16; d <<= 1) {
            const int u = __shfl_up(ws2, d, 16);
            if (t >= d) ws2 += u;
        }
        wsum[t] = ws2;
    }
    __syncthreads();
    const int waveoff = (w == 0) ? 0 : wsum[w - 1];
    if (idx < NN) off[idx] = s - v + waveoff + partials[b];
    if (idx == 0) off[NN] = NE;
}

// ---------------- init coarse-bucket cursors from off ----------------
__global__ void init_bcur(const int* __restrict__ off, int* __restrict__ bcur) {
    const int b = threadIdx.x;
    if (b < NBUCK) bcur[b] = off[b << BSHIFT];
}

// ---------------- pass 1: bin edges into 512-node buckets ----------------
__global__ __launch_bounds__(256) void bin_edges(const int* __restrict__ es,
                                                 const int* __restrict__ ed,
                                                 const float* __restrict__ ew,
                                                 int* __restrict__ bcur,
                                                 int2* __restrict__ srcw2b,
                                                 int* __restrict__ dstb) {
    __shared__ int hist[NBUCK];
    __shared__ int base[NBUCK];
    const int tid = threadIdx.x;
    const int e0 = blockIdx.x * 4096;
    for (int i = tid; i < NBUCK; i += 256) hist[i] = 0;
    __syncthreads();
    int d[16];
#pragma unroll
    for (int j = 0; j < 16; ++j) {
        const int e = e0 + j * 256 + tid;
        d[j] = (e < NE) ? ed[e] : -1;
        if (d[j] >= 0) atomicAdd(&hist[d[j] >> BSHIFT], 1);
    }
    __syncthreads();
    for (int i = tid; i < NBUCK; i += 256) base[i] = atomicAdd(&bcur[i], hist[i]);
    __syncthreads();
    for (int i = tid; i < NBUCK; i += 256) hist[i] = 0;
    __syncthreads();
#pragma unroll
    for (int j = 0; j < 16; ++j) {
        const int e = e0 + j * 256 + tid;
        if (d[j] >= 0) {
            const int b = d[j] >> BSHIFT;
            const int l = atomicAdd(&hist[b], 1);
            const int p = base[b] + l;
            srcw2b[p] = make_int2(es[e], __float_as_int(ew[e]));
            dstb[p] = d[j];
        }
    }
}

// ---------------- pass 2: place within L2-resident bucket windows ----------------
__global__ void place_edges(const int2* __restrict__ srcw2b, const int* __restrict__ dstb,
                            int* __restrict__ cursor, int2* __restrict__ edges2) {
    const int e = blockIdx.x * blockDim.x + threadIdx.x;
    if (e < NE) {
        const int dd = dstb[e];
        const int p = atomicAdd(&cursor[dd], 1);
        edges2[p] = srcw2b[e];
    }
}

// ---------------- CSR SpMM (bf16 gather) + bias + relu ----------------
__global__ __launch_bounds__(256) void spmm_csr(const __hip_bfloat16* __restrict__ feat,
                                                const int* __restrict__ off,
                                                const int2* __restrict__ edges2,
                                                const float* __restrict__ b,
                                                float* __restrict__ out) {
    const int w = threadIdx.x >> 6;
    const int lane = threadIdx.x & 63;
    const int n = blockIdx.x * 4 + w;
    const int beg = off[n];
    const int end = off[n + 1];
    float acc = 0.f;
    int i = beg;
    for (; i + 3 < end; i += 4) {
        const int2 e0 = edges2[i];
        const int2 e1 = edges2[i + 1];
        const int2 e2 = edges2[i + 2];
        const int2 e3 = edges2[i + 3];
        const float f0 = __bfloat162float(feat[(size_t)e0.x * 64 + lane]);
        const float f1 = __bfloat162float(feat[(size_t)e1.x * 64 + lane]);
        const float f2 = __bfloat162float(feat[(size_t)e2.x * 64 + lane]);
        const float f3 = __bfloat162float(feat[(size_t)e3.x * 64 + lane]);
        acc = fmaf(f0, __int_as_float(e0.y), acc);
        acc = fmaf(f1, __int_as_float(e1.y), acc);
        acc = fmaf(f2, __int_as_float(e2.y), acc);
        acc = fmaf(f3, __int_as_float(e3.y), acc);
    }
    for (; i < end; ++i) {
        const int2 e = edges2[i];
        acc = fmaf(__bfloat162float(feat[(size_t)e.x * 64 + lane]), __int_as_float(e.y), acc);
    }
    const float v = acc + b[lane];
    out[(size_t)n * 64 + lane] = v > 0.f ? v : 0.f;
}

// ============ head: 128 rows x 40 cols per block, register-tiled ============
__global__ __launch_bounds__(256) void head_tile(const float* __restrict__ h2,
                                                 const float* __restrict__ Wl,
                                                 const float* __restrict__ bl,
                                                 float* __restrict__ logits,
                                                 float* __restrict__ logp) {
    __shared__ float Wt[40 * 68];      // 10880 B
    __shared__ float Xs[HROWS * 68];   // 34816 B
    __shared__ float bs[40];
    const int tid = threadIdx.x;
    const int row0 = blockIdx.x * HROWS;
    for (int i = tid; i < 64 * 40; i += 256) {
        const int k = i / 40, c = i - k * 40;
        Wt[c * 68 + k] = Wl[i];
    }
    if (tid < 40) bs[tid] = bl[tid];
    for (int i = tid; i < HROWS * 16; i += 256) {
        const int r = i >> 4, kq = i & 15;
        const int row = row0 + r;
        float4 v = make_float4(0.f, 0.f, 0.f, 0.f);
        if (row < NN) v = *(const float4*)(h2 + (size_t)row * 64 + kq * 4);
        *(float4*)(&Xs[r * 68 + kq * 4]) = v;
    }
    __syncthreads();
    const int tcol = tid & 3;
    const int trow = tid >> 2;
    float acc[2][10] = {};
    const float* xb0 = &Xs[trow * 68];
    const float* xb1 = &Xs[(trow + 64) * 68];
    const float* wb = &Wt[(tcol * 10) * 68];
    for (int k = 0; k < 64; k += 4) {
        const float4 x0 = *(const float4*)(xb0 + k);
        const float4 x1 = *(const float4*)(xb1 + k);
#pragma unroll
        for (int c = 0; c < 10; ++c) {
            const float4 wv = *(const float4*)(wb + c * 68 + k);
            acc[0][c] = fmaf(x0.x, wv.x, acc[0][c]);
            acc[0][c] = fmaf(x0.y, wv.y, acc[0][c]);
            acc[0][c] = fmaf(x0.z, wv.z, acc[0][c]);
            acc[0][c] = fmaf(x0.w, wv.w, acc[0][c]);
            acc[1][c] = fmaf(x1.x, wv.x, acc[1][c]);
            acc[1][c] = fmaf(x1.y, wv.y, acc[1][c]);
            acc[1][c] = fmaf(x1.z, wv.z, acc[1][c]);
            acc[1][c] = fmaf(x1.w, wv.w, acc[1][c]);
        }
    }
    float bv[10];
#pragma unroll
    for (int c = 0; c < 10; ++c) bv[c] = bs[tcol * 10 + c];
#pragma unroll
    for (int r = 0; r < 2; ++r) {
        const int row = row0 + trow + r * 64;
#pragma unroll
        for (int c = 0; c < 10; ++c) acc[r][c] += bv[c];
        float m = acc[r][0];
#pragma unroll
        for (int c = 1; c < 10; ++c) m = fmaxf(m, acc[r][c]);
        m = fmaxf(m, __shfl_xor(m, 1, 64));
        m = fmaxf(m, __shfl_xor(m, 2, 64));
        float s = 0.f;
#pragma unroll
        for (int c = 0; c < 10; ++c) s += expf(acc[r][c] - m);
        s += __shfl_xor(s, 1, 64);
        s += __shfl_xor(s, 2, 64);
        const float lse = logf(s) + m;
        if (row < NN) {
            float* lg = logits + (size_t)row * 40 + tcol * 10;
            float* lp = logp   + (size_t)row * 40 + tcol * 10;
#pragma unroll
            for (int c = 0; c < 10; c += 2) {
                *(float2*)(lg + c) = make_float2(acc[r][c], acc[r][c + 1]);
                *(float2*)(lp + c) = make_float2(acc[r][c] - lse, acc[r][c + 1] - lse);
            }
        }
    }
}

extern "C" void kernel_launch(void* const* d_in, const int* in_sizes, int n_in,
                              void* d_out, int out_size, void* d_ws, size_t ws_size,
                              hipStream_t stream) {
    const float* x  = (const float*)d_in[0];
    const int*   es = (const int*)  d_in[1];
    const int*   ed = (const int*)  d_in[2];
    const float* ew = (const float*)d_in[3];
    const float* W1 = (const float*)d_in[4];
    const float* b1 = (const float*)d_in[5];
    const float* W2 = (const float*)d_in[6];
    const float* b2 = (const float*)d_in[7];
    const float* Wl = (const float*)d_in[8];
    const float* bl = (const float*)d_in[9];

    float* out    = (float*)d_out;
    float* logp   = out;                          // [N,40]
    float* h1     = logp + (size_t)NN * 40;       // [N,64]
    float* h2     = h1   + (size_t)NN * 64;       // [N,64]
    float* logits = h2   + (size_t)NN * 64;       // [N,40]

    // workspace layout
    char* wsb = (char*)d_ws;
    __hip_bfloat16* ws0 = (__hip_bfloat16*)wsb;                 // [N,64] bf16 12.8 MB (GEMM out)
    int2*  srcw2b  = (int2*)wsb;                                // binned edges (overlays ws0)
    int*   dstb    = (int*)(wsb + (size_t)NE * 8);              // binned dsts
    int2*  edges2  = (int2*)(wsb + (size_t)NN * 64 * 4);        // [E] 12.8 MB
    int*   off     = (int*)((char*)edges2 + (size_t)NE * 8);    // [N+1]
    int*   cursor  = off + (NN + 1);                            // [N]
    int*   partials = cursor + NN;                              // [NBLK]
    int*   bcur    = partials + NBLK;                           // [NBUCK]

    const int gemmGrid = (NN + 63) / 64;

    // ---- build dest-sorted CSR (once, reused by both layers) ----
    hipMemsetAsync(cursor, 0, (size_t)NN * 4, stream);
    hist_dst<<<NE / 256, 256, 0, stream>>>(ed, cursor);
    scan_phase1<<<NBLK, SCAN_B, 0, stream>>>(cursor, partials);
    scan_phase2<<<1, 128, 0, stream>>>(partials);
    scan_phase3<<<NBLK, SCAN_B, 0, stream>>>(cursor, partials, off);
    init_bcur<<<1, 256, 0, stream>>>(off, bcur);
    bin_edges<<<(NE + 4095) / 4096, 256, 0, stream>>>(es, ed, ew, bcur, srcw2b, dstb);
    hipMemcpyAsync(cursor, off, (size_t)NN * 4, hipMemcpyDeviceToDevice, stream);
    place_edges<<<(NE + 255) / 256, 256, 0, stream>>>(srcw2b, dstb, cursor, edges2);

    // ---- layer 1 ----
    gemm1_tile<<<gemmGrid, 256, 0, stream>>>(x, W1, ws0);
    spmm_csr<<<NN / 4, 256, 0, stream>>>(ws0, off, edges2, b1, h1);

    // ---- layer 2 ----
    gemm2_tile<<<gemmGrid, 256, 0, stream>>>(h1, W2, ws0);
    spmm_csr<<<NN / 4, 256, 0, stream>>>(ws0, off, edges2, b2, h2);

    // ---- head ----
    head_tile<<<(NN + HROWS - 1) / HROWS, 256, 0, stream>>>(h2, Wl, bl, logits, logp);
}

// Round 9
// 380.327 us; speedup vs baseline: 2.7540x; 1.0765x over previous
//
#include <hip/hip_runtime.h>
#include <hip/hip_bf16.h>
#include <math.h>

#define NN 100000
#define NE 1600000
#define SCAN_B 1024
#define NBLK ((NN + SCAN_B - 1) / SCAN_B)   // 98
#define BSHIFT 9
#define NBUCK ((NN + (1 << BSHIFT) - 1) >> BSHIFT)   // 196
#define HROWS 128

// ============ GEMM1: x[N,128] @ W1[128,64] -> out_bf16[N,64] ============
__global__ __launch_bounds__(256, 3) void gemm1_tile(const float* __restrict__ x,
                                                     const float* __restrict__ W,
                                                     __hip_bfloat16* __restrict__ out) {
    __shared__ float Wt[64 * 132];     // 33792 B
    __shared__ float Xs[64 * 68];      // 17408 B
    const int tid = threadIdx.x;
    const int row0 = blockIdx.x * 64;
    for (int i = tid; i < 64 * 128; i += 256) {
        const int c = i >> 7, k = i & 127;
        Wt[c * 132 + k] = W[k * 64 + c];
    }
    const int tc = tid & 15;
    const int tr = tid >> 4;
    float acc[4][4] = {};
    const float* wb = &Wt[tc * 132];
    for (int kh = 0; kh < 2; ++kh) {
        __syncthreads();
        for (int i = tid; i < 64 * 16; i += 256) {
            const int r = i >> 4, kq = i & 15;
            const int row = row0 + r;
            float4 v = make_float4(0.f, 0.f, 0.f, 0.f);
            if (row < NN) v = *(const float4*)(x + (size_t)row * 128 + kh * 64 + kq * 4);
            *(float4*)(&Xs[r * 68 + kq * 4]) = v;
        }
        __syncthreads();
        const float* xb = &Xs[(tr * 4) * 68];
#pragma unroll 2
        for (int k = 0; k < 64; k += 4) {
            float4 xv[4], wv[4];
#pragma unroll
            for (int r = 0; r < 4; ++r) xv[r] = *(const float4*)(xb + r * 68 + k);
#pragma unroll
            for (int c = 0; c < 4; ++c) wv[c] = *(const float4*)(wb + c * (16 * 132) + kh * 64 + k);
#pragma unroll
            for (int r = 0; r < 4; ++r)
#pragma unroll
                for (int c = 0; c < 4; ++c) {
                    acc[r][c] = fmaf(xv[r].x, wv[c].x, acc[r][c]);
                    acc[r][c] = fmaf(xv[r].y, wv[c].y, acc[r][c]);
                    acc[r][c] = fmaf(xv[r].z, wv[c].z, acc[r][c]);
                    acc[r][c] = fmaf(xv[r].w, wv[c].w, acc[r][c]);
                }
        }
    }
#pragma unroll
    for (int r = 0; r < 4; ++r) {
        const int row = row0 + tr * 4 + r;
        if (row < NN) {
#pragma unroll
            for (int c = 0; c < 4; ++c)
                out[(size_t)row * 64 + tc + c * 16] = __float2bfloat16(acc[r][c]);
        }
    }
}

// ============ GEMM2: h[N,64] @ W2[64,64] -> out_bf16[N,64] ============
__global__ __launch_bounds__(256, 3) void gemm2_tile(const float* __restrict__ h,
                                                     const float* __restrict__ W,
                                                     __hip_bfloat16* __restrict__ out) {
    __shared__ float Wt[64 * 68];
    __shared__ float Xs[64 * 68];
    const int tid = threadIdx.x;
    const int row0 = blockIdx.x * 64;
    for (int i = tid; i < 64 * 64; i += 256) {
        const int c = i >> 6, k = i & 63;
        Wt[c * 68 + k] = W[k * 64 + c];
    }
    for (int i = tid; i < 64 * 16; i += 256) {
        const int r = i >> 4, kq = i & 15;
        const int row = row0 + r;
        float4 v = make_float4(0.f, 0.f, 0.f, 0.f);
        if (row < NN) v = *(const float4*)(h + (size_t)row * 64 + kq * 4);
        *(float4*)(&Xs[r * 68 + kq * 4]) = v;
    }
    __syncthreads();
    const int tc = tid & 15;
    const int tr = tid >> 4;
    float acc[4][4] = {};
    const float* xb = &Xs[(tr * 4) * 68];
    const float* wb = &Wt[tc * 68];
#pragma unroll 2
    for (int k = 0; k < 64; k += 4) {
        float4 xv[4], wv[4];
#pragma unroll
        for (int r = 0; r < 4; ++r) xv[r] = *(const float4*)(xb + r * 68 + k);
#pragma unroll
        for (int c = 0; c < 4; ++c) wv[c] = *(const float4*)(wb + c * (16 * 68) + k);
#pragma unroll
        for (int r = 0; r < 4; ++r)
#pragma unroll
            for (int c = 0; c < 4; ++c) {
                acc[r][c] = fmaf(xv[r].x, wv[c].x, acc[r][c]);
                acc[r][c] = fmaf(xv[r].y, wv[c].y, acc[r][c]);
                acc[r][c] = fmaf(xv[r].z, wv[c].z, acc[r][c]);
                acc[r][c] = fmaf(xv[r].w, wv[c].w, acc[r][c]);
            }
    }
#pragma unroll
    for (int r = 0; r < 4; ++r) {
        const int row = row0 + tr * 4 + r;
        if (row < NN) {
#pragma unroll
            for (int c = 0; c < 4; ++c)
                out[(size_t)row * 64 + tc + c * 16] = __float2bfloat16(acc[r][c]);
        }
    }
}

// ---------------- CSR build: histogram of destinations ----------------
__global__ void hist_dst(const int* __restrict__ ed, int* __restrict__ counts) {
    const int e = blockIdx.x * blockDim.x + threadIdx.x;
    atomicAdd(&counts[ed[e]], 1);
}

// ---------------- hierarchical scan: phase 1 — per-block reduce ----------------
__global__ void scan_phase1(const int* __restrict__ counts, int* __restrict__ partials) {
    const int idx = blockIdx.x * SCAN_B + threadIdx.x;
    int v = (idx < NN) ? counts[idx] : 0;
    for (int off = 32; off; off >>= 1) v += __shfl_xor(v, off, 64);
    __shared__ int wsum[16];
    if ((threadIdx.x & 63) == 0) wsum[threadIdx.x >> 6] = v;
    __syncthreads();
    if (threadIdx.x < 16) {
        int s = wsum[threadIdx.x];
        for (int off = 8; off; off >>= 1) s += __shfl_xor(s, off, 16);
        if (threadIdx.x == 0) partials[blockIdx.x] = s;
    }
}

// ---------------- phase 2 — exclusive scan of the 98 partials ----------------
__global__ void scan_phase2(int* __restrict__ partials) {
    __shared__ int p[128];
    const int t = threadIdx.x;
    const int v = (t < NBLK) ? partials[t] : 0;
    p[t] = v;
    __syncthreads();
    for (int d = 1; d < 128; d <<= 1) {
        const int u = (t >= d) ? p[t - d] : 0;
        __syncthreads();
        p[t] += u;
        __syncthreads();
    }
    if (t < NBLK) partials[t] = p[t] - v;
}

// ---------------- phase 3 — block-local exclusive scan + block offset ----------------
__global__ void scan_phase3(const int* __restrict__ counts, const int* __restrict__ partials,
                            int* __restrict__ off) {
    const int b = blockIdx.x;
    const int t = threadIdx.x;
    const int idx = b * SCAN_B + t;
    const int lane = t & 63;
    const int w = t >> 6;
    const int v = (idx < NN) ? counts[idx] : 0;
    int s = v;
    for (int d = 1; d < 64; d <<= 1) {
        const int u = __shfl_up(s, d, 64);
        if (lane >= d) s += u;
    }
    __shared__ int wsum[16];
    if (lane == 63) wsum[w] = s;
    __syncthreads();
    if (t < 16) {
        int ws2 = wsum[t];
        for (int d = 1; d < 16; d <<= 1) {
            const int u = __shfl_up(ws2, d, 16);
            if (t >= d) ws2 += u;
        }
        wsum[t] = ws2;
    }
    __syncthreads();
    const int waveoff = (w == 0) ? 0 : wsum[w - 1];
    if (idx < NN) off[idx] = s - v + waveoff + partials[b];
    if (idx == 0) off[NN] = NE;
}

// ---------------- init coarse-bucket cursors from off ----------------
__global__ void init_bcur(const int* __restrict__ off, int* __restrict__ bcur) {
    const int b = threadIdx.x;
    if (b < NBUCK) bcur[b] = off[b << BSHIFT];
}

// ---------------- pass 1: bin edges into 512-node buckets ----------------
__global__ __launch_bounds__(256) void bin_edges(const int* __restrict__ es,
                                                 const int* __restrict__ ed,
                                                 const float* __restrict__ ew,
                                                 int* __restrict__ bcur,
                                                 int2* __restrict__ srcw2b,
                                                 int* __restrict__ dstb) {
    __shared__ int hist[NBUCK];
    __shared__ int base[NBUCK];
    const int tid = threadIdx.x;
    const int e0 = blockIdx.x * 4096;
    for (int i = tid; i < NBUCK; i += 256) hist[i] = 0;
    __syncthreads();
    int d[16];
#pragma unroll
    for (int j = 0; j < 16; ++j) {
        const int e = e0 + j * 256 + tid;
        d[j] = (e < NE) ? ed[e] : -1;
        if (d[j] >= 0) atomicAdd(&hist[d[j] >> BSHIFT], 1);
    }
    __syncthreads();
    for (int i = tid; i < NBUCK; i += 256) base[i] = atomicAdd(&bcur[i], hist[i]);
    __syncthreads();
    for (int i = tid; i < NBUCK; i += 256) hist[i] = 0;
    __syncthreads();
#pragma unroll
    for (int j = 0; j < 16; ++j) {
        const int e = e0 + j * 256 + tid;
        if (d[j] >= 0) {
            const int b = d[j] >> BSHIFT;
            const int l = atomicAdd(&hist[b], 1);
            const int p = base[b] + l;
            srcw2b[p] = make_int2(es[e], __float_as_int(ew[e]));
            dstb[p] = d[j];
        }
    }
}

// ---------------- pass 2: place within L2-resident bucket windows ----------------
__global__ void place_edges(const int2* __restrict__ srcw2b, const int* __restrict__ dstb,
                            int* __restrict__ cursor, int2* __restrict__ edges2) {
    const int e = blockIdx.x * blockDim.x + threadIdx.x;
    if (e < NE) {
        const int dd = dstb[e];
        const int p = atomicAdd(&cursor[dd], 1);
        edges2[p] = srcw2b[e];
    }
}

// ---------------- CSR SpMM (bf16 gather, 2 edges/instr) + bias + relu ----------------
// lane = (p, f2): p = lane>>5 selects edge parity, f2 = lane&31 selects feature pair.
// Each feature-gather wave instruction serves TWO edges (2 x 128 B).
__global__ __launch_bounds__(256) void spmm_csr(const __hip_bfloat16* __restrict__ feat,
                                                const int* __restrict__ off,
                                                const int2* __restrict__ edges2,
                                                const float* __restrict__ b,
                                                float* __restrict__ out) {
    const int w = threadIdx.x >> 6;
    const int lane = threadIdx.x & 63;
    const int n = blockIdx.x * 4 + w;
    const int beg = off[n];
    const int end = off[n + 1];
    const int p = lane >> 5;
    const int f2 = lane & 31;
    float ax = 0.f, ay = 0.f;
    int i = beg;
    for (; i + 7 < end; i += 8) {               // 8 edges per iter, 4 gathers in flight
        const int2 e0 = edges2[i     + p];
        const int2 e1 = edges2[i + 2 + p];
        const int2 e2 = edges2[i + 4 + p];
        const int2 e3 = edges2[i + 6 + p];
        const unsigned g0 = *(const unsigned*)(feat + (size_t)e0.x * 64 + f2 * 2);
        const unsigned g1 = *(const unsigned*)(feat + (size_t)e1.x * 64 + f2 * 2);
        const unsigned g2 = *(const unsigned*)(feat + (size_t)e2.x * 64 + f2 * 2);
        const unsigned g3 = *(const unsigned*)(feat + (size_t)e3.x * 64 + f2 * 2);
        const float w0 = __int_as_float(e0.y), w1 = __int_as_float(e1.y);
        const float w2 = __int_as_float(e2.y), w3 = __int_as_float(e3.y);
        ax = fmaf(__uint_as_float(g0 << 16), w0, ax);
        ay = fmaf(__uint_as_float(g0 & 0xffff0000u), w0, ay);
        ax = fmaf(__uint_as_float(g1 << 16), w1, ax);
        ay = fmaf(__uint_as_float(g1 & 0xffff0000u), w1, ay);
        ax = fmaf(__uint_as_float(g2 << 16), w2, ax);
        ay = fmaf(__uint_as_float(g2 & 0xffff0000u), w2, ay);
        ax = fmaf(__uint_as_float(g3 << 16), w3, ax);
        ay = fmaf(__uint_as_float(g3 & 0xffff0000u), w3, ay);
    }
    for (; i + 1 < end; i += 2) {               // pair remainder
        const int2 e = edges2[i + p];
        const unsigned g = *(const unsigned*)(feat + (size_t)e.x * 64 + f2 * 2);
        const float wv = __int_as_float(e.y);
        ax = fmaf(__uint_as_float(g << 16), wv, ax);
        ay = fmaf(__uint_as_float(g & 0xffff0000u), wv, ay);
    }
    if (i < end && p == 0) {                    // odd edge: half-wave only
        const int2 e = edges2[i];
        const unsigned g = *(const unsigned*)(feat + (size_t)e.x * 64 + f2 * 2);
        const float wv = __int_as_float(e.y);
        ax = fmaf(__uint_as_float(g << 16), wv, ax);
        ay = fmaf(__uint_as_float(g & 0xffff0000u), wv, ay);
    }
    ax += __shfl_xor(ax, 32, 64);
    ay += __shfl_xor(ay, 32, 64);
    if (p == 0) {
        float vx = ax + b[f2 * 2];
        float vy = ay + b[f2 * 2 + 1];
        vx = vx > 0.f ? vx : 0.f;
        vy = vy > 0.f ? vy : 0.f;
        *(float2*)(out + (size_t)n * 64 + f2 * 2) = make_float2(vx, vy);
    }
}

// ============ head: 128 rows x 40 cols per block, register-tiled ============
__global__ __launch_bounds__(256) void head_tile(const float* __restrict__ h2,
                                                 const float* __restrict__ Wl,
                                                 const float* __restrict__ bl,
                                                 float* __restrict__ logits,
                                                 float* __restrict__ logp) {
    __shared__ float Wt[40 * 68];      // 10880 B
    __shared__ float Xs[HROWS * 68];   // 34816 B
    __shared__ float bs[40];
    const int tid = threadIdx.x;
    const int row0 = blockIdx.x * HROWS;
    for (int i = tid; i < 64 * 40; i += 256) {
        const int k = i / 40, c = i - k * 40;
        Wt[c * 68 + k] = Wl[i];
    }
    if (tid < 40) bs[tid] = bl[tid];
    for (int i = tid; i < HROWS * 16; i += 256) {
        const int r = i >> 4, kq = i & 15;
        const int row = row0 + r;
        float4 v = make_float4(0.f, 0.f, 0.f, 0.f);
        if (row < NN) v = *(const float4*)(h2 + (size_t)row * 64 + kq * 4);
        *(float4*)(&Xs[r * 68 + kq * 4]) = v;
    }
    __syncthreads();
    const int tcol = tid & 3;
    const int trow = tid >> 2;
    float acc[2][10] = {};
    const float* xb0 = &Xs[trow * 68];
    const float* xb1 = &Xs[(trow + 64) * 68];
    const float* wb = &Wt[(tcol * 10) * 68];
    for (int k = 0; k < 64; k += 4) {
        const float4 x0 = *(const float4*)(xb0 + k);
        const float4 x1 = *(const float4*)(xb1 + k);
#pragma unroll
        for (int c = 0; c < 10; ++c) {
            const float4 wv = *(const float4*)(wb + c * 68 + k);
            acc[0][c] = fmaf(x0.x, wv.x, acc[0][c]);
            acc[0][c] = fmaf(x0.y, wv.y, acc[0][c]);
            acc[0][c] = fmaf(x0.z, wv.z, acc[0][c]);
            acc[0][c] = fmaf(x0.w, wv.w, acc[0][c]);
            acc[1][c] = fmaf(x1.x, wv.x, acc[1][c]);
            acc[1][c] = fmaf(x1.y, wv.y, acc[1][c]);
            acc[1][c] = fmaf(x1.z, wv.z, acc[1][c]);
            acc[1][c] = fmaf(x1.w, wv.w, acc[1][c]);
        }
    }
    float bv[10];
#pragma unroll
    for (int c = 0; c < 10; ++c) bv[c] = bs[tcol * 10 + c];
#pragma unroll
    for (int r = 0; r < 2; ++r) {
        const int row = row0 + trow + r * 64;
#pragma unroll
        for (int c = 0; c < 10; ++c) acc[r][c] += bv[c];
        float m = acc[r][0];
#pragma unroll
        for (int c = 1; c < 10; ++c) m = fmaxf(m, acc[r][c]);
        m = fmaxf(m, __shfl_xor(m, 1, 64));
        m = fmaxf(m, __shfl_xor(m, 2, 64));
        float s = 0.f;
#pragma unroll
        for (int c = 0; c < 10; ++c) s += expf(acc[r][c] - m);
        s += __shfl_xor(s, 1, 64);
        s += __shfl_xor(s, 2, 64);
        const float lse = logf(s) + m;
        if (row < NN) {
            float* lg = logits + (size_t)row * 40 + tcol * 10;
            float* lp = logp   + (size_t)row * 40 + tcol * 10;
#pragma unroll
            for (int c = 0; c < 10; c += 2) {
                *(float2*)(lg + c) = make_float2(acc[r][c], acc[r][c + 1]);
                *(float2*)(lp + c) = make_float2(acc[r][c] - lse, acc[r][c + 1] - lse);
            }
        }
    }
}

extern "C" void kernel_launch(void* const* d_in, const int* in_sizes, int n_in,
                              void* d_out, int out_size, void* d_ws, size_t ws_size,
                              hipStream_t stream) {
    const float* x  = (const float*)d_in[0];
    const int*   es = (const int*)  d_in[1];
    const int*   ed = (const int*)  d_in[2];
    const float* ew = (const float*)d_in[3];
    const float* W1 = (const float*)d_in[4];
    const float* b1 = (const float*)d_in[5];
    const float* W2 = (const float*)d_in[6];
    const float* b2 = (const float*)d_in[7];
    const float* Wl = (const float*)d_in[8];
    const float* bl = (const float*)d_in[9];

    float* out    = (float*)d_out;
    float* logp   = out;                          // [N,40]
    float* h1     = logp + (size_t)NN * 40;       // [N,64]
    float* h2     = h1   + (size_t)NN * 64;       // [N,64]
    float* logits = h2   + (size_t)NN * 64;       // [N,40]

    // workspace layout
    char* wsb = (char*)d_ws;
    __hip_bfloat16* ws0 = (__hip_bfloat16*)wsb;                 // [N,64] bf16 12.8 MB (GEMM out)
    int2*  srcw2b  = (int2*)wsb;                                // binned edges (overlays ws0)
    int*   dstb    = (int*)(wsb + (size_t)NE * 8);              // binned dsts
    int2*  edges2  = (int2*)(wsb + (size_t)NN * 64 * 4);        // [E] 12.8 MB
    int*   off     = (int*)((char*)edges2 + (size_t)NE * 8);    // [N+1]
    int*   cursor  = off + (NN + 1);                            // [N]
    int*   partials = cursor + NN;                              // [NBLK]
    int*   bcur    = partials + NBLK;                           // [NBUCK]

    const int gemmGrid = (NN + 63) / 64;

    // ---- build dest-sorted CSR (once, reused by both layers) ----
    hipMemsetAsync(cursor, 0, (size_t)NN * 4, stream);
    hist_dst<<<NE / 256, 256, 0, stream>>>(ed, cursor);
    scan_phase1<<<NBLK, SCAN_B, 0, stream>>>(cursor, partials);
    scan_phase2<<<1, 128, 0, stream>>>(partials);
    scan_phase3<<<NBLK, SCAN_B, 0, stream>>>(cursor, partials, off);
    init_bcur<<<1, 256, 0, stream>>>(off, bcur);
    bin_edges<<<(NE + 4095) / 4096, 256, 0, stream>>>(es, ed, ew, bcur, srcw2b, dstb);
    hipMemcpyAsync(cursor, off, (size_t)NN * 4, hipMemcpyDeviceToDevice, stream);
    place_edges<<<(NE + 255) / 256, 256, 0, stream>>>(srcw2b, dstb, cursor, edges2);

    // ---- layer 1 ----
    gemm1_tile<<<gemmGrid, 256, 0, stream>>>(x, W1, ws0);
    spmm_csr<<<NN / 4, 256, 0, stream>>>(ws0, off, edges2, b1, h1);

    // ---- layer 2 ----
    gemm2_tile<<<gemmGrid, 256, 0, stream>>>(h1, W2, ws0);
    spmm_csr<<<NN / 4, 256, 0, stream>>>(ws0, off, edges2, b2, h2);

    // ---- head ----
    head_tile<<<(NN + HROWS - 1) / HROWS, 256, 0, stream>>>(h2, Wl, bl, logits, logp);
}

// Round 10
// 310.772 us; speedup vs baseline: 3.3703x; 1.2238x over previous
//
#include <hip/hip_runtime.h>
#include <hip/hip_bf16.h>
#include <math.h>

#define NN 100000
#define NE 1600000
#define BSHIFT 9
#define NBUCK ((NN + (1 << BSHIFT) - 1) >> BSHIFT)   // 196
#define HROWS 128

// ============ GEMM1: x[N,128] @ W1[128,64] -> out_bf16[N,64] ============
__global__ __launch_bounds__(256, 3) void gemm1_tile(const float* __restrict__ x,
                                                     const float* __restrict__ W,
                                                     __hip_bfloat16* __restrict__ out) {
    __shared__ float Wt[64 * 132];     // 33792 B
    __shared__ float Xs[64 * 68];      // 17408 B
    const int tid = threadIdx.x;
    const int row0 = blockIdx.x * 64;
    for (int i = tid; i < 64 * 128; i += 256) {
        const int c = i >> 7, k = i & 127;
        Wt[c * 132 + k] = W[k * 64 + c];
    }
    const int tc = tid & 15;
    const int tr = tid >> 4;
    float acc[4][4] = {};
    const float* wb = &Wt[tc * 132];
    for (int kh = 0; kh < 2; ++kh) {
        __syncthreads();
        for (int i = tid; i < 64 * 16; i += 256) {
            const int r = i >> 4, kq = i & 15;
            const int row = row0 + r;
            float4 v = make_float4(0.f, 0.f, 0.f, 0.f);
            if (row < NN) v = *(const float4*)(x + (size_t)row * 128 + kh * 64 + kq * 4);
            *(float4*)(&Xs[r * 68 + kq * 4]) = v;
        }
        __syncthreads();
        const float* xb = &Xs[(tr * 4) * 68];
#pragma unroll 2
        for (int k = 0; k < 64; k += 4) {
            float4 xv[4], wv[4];
#pragma unroll
            for (int r = 0; r < 4; ++r) xv[r] = *(const float4*)(xb + r * 68 + k);
#pragma unroll
            for (int c = 0; c < 4; ++c) wv[c] = *(const float4*)(wb + c * (16 * 132) + kh * 64 + k);
#pragma unroll
            for (int r = 0; r < 4; ++r)
#pragma unroll
                for (int c = 0; c < 4; ++c) {
                    acc[r][c] = fmaf(xv[r].x, wv[c].x, acc[r][c]);
                    acc[r][c] = fmaf(xv[r].y, wv[c].y, acc[r][c]);
                    acc[r][c] = fmaf(xv[r].z, wv[c].z, acc[r][c]);
                    acc[r][c] = fmaf(xv[r].w, wv[c].w, acc[r][c]);
                }
        }
    }
#pragma unroll
    for (int r = 0; r < 4; ++r) {
        const int row = row0 + tr * 4 + r;
        if (row < NN) {
#pragma unroll
            for (int c = 0; c < 4; ++c)
                out[(size_t)row * 64 + tc + c * 16] = __float2bfloat16(acc[r][c]);
        }
    }
}

// ============ GEMM2: h[N,64] @ W2[64,64] -> out_bf16[N,64] ============
__global__ __launch_bounds__(256, 3) void gemm2_tile(const float* __restrict__ h,
                                                     const float* __restrict__ W,
                                                     __hip_bfloat16* __restrict__ out) {
    __shared__ float Wt[64 * 68];
    __shared__ float Xs[64 * 68];
    const int tid = threadIdx.x;
    const int row0 = blockIdx.x * 64;
    for (int i = tid; i < 64 * 64; i += 256) {
        const int c = i >> 6, k = i & 63;
        Wt[c * 68 + k] = W[k * 64 + c];
    }
    for (int i = tid; i < 64 * 16; i += 256) {
        const int r = i >> 4, kq = i & 15;
        const int row = row0 + r;
        float4 v = make_float4(0.f, 0.f, 0.f, 0.f);
        if (row < NN) v = *(const float4*)(h + (size_t)row * 64 + kq * 4);
        *(float4*)(&Xs[r * 68 + kq * 4]) = v;
    }
    __syncthreads();
    const int tc = tid & 15;
    const int tr = tid >> 4;
    float acc[4][4] = {};
    const float* xb = &Xs[(tr * 4) * 68];
    const float* wb = &Wt[tc * 68];
#pragma unroll 2
    for (int k = 0; k < 64; k += 4) {
        float4 xv[4], wv[4];
#pragma unroll
        for (int r = 0; r < 4; ++r) xv[r] = *(const float4*)(xb + r * 68 + k);
#pragma unroll
        for (int c = 0; c < 4; ++c) wv[c] = *(const float4*)(wb + c * (16 * 68) + k);
#pragma unroll
        for (int r = 0; r < 4; ++r)
#pragma unroll
            for (int c = 0; c < 4; ++c) {
                acc[r][c] = fmaf(xv[r].x, wv[c].x, acc[r][c]);
                acc[r][c] = fmaf(xv[r].y, wv[c].y, acc[r][c]);
                acc[r][c] = fmaf(xv[r].z, wv[c].z, acc[r][c]);
                acc[r][c] = fmaf(xv[r].w, wv[c].w, acc[r][c]);
            }
    }
#pragma unroll
    for (int r = 0; r < 4; ++r) {
        const int row = row0 + tr * 4 + r;
        if (row < NN) {
#pragma unroll
            for (int c = 0; c < 4; ++c)
                out[(size_t)row * 64 + tc + c * 16] = __float2bfloat16(acc[r][c]);
        }
    }
}

// ---------------- bucket-level histogram (LDS-privatized) ----------------
__global__ __launch_bounds__(256) void bucket_hist(const int* __restrict__ ed,
                                                   int* __restrict__ bucketCnt) {
    __shared__ int hist[NBUCK];
    const int tid = threadIdx.x;
    const int e0 = blockIdx.x * 4096;
    for (int i = tid; i < NBUCK; i += 256) hist[i] = 0;
    __syncthreads();
#pragma unroll
    for (int j = 0; j < 16; ++j) {
        const int e = e0 + j * 256 + tid;
        if (e < NE) atomicAdd(&hist[ed[e] >> BSHIFT], 1);
    }
    __syncthreads();
    for (int i = tid; i < NBUCK; i += 256)
        if (hist[i]) atomicAdd(&bucketCnt[i], hist[i]);
}

// ---------------- scan 196 bucket counts -> bucketOff + bcur ----------------
__global__ void bucket_scan(const int* __restrict__ bucketCnt, int* __restrict__ bucketOff,
                            int* __restrict__ bcur) {
    __shared__ int p[256];
    const int t = threadIdx.x;
    const int v = (t < NBUCK) ? bucketCnt[t] : 0;
    p[t] = v;
    __syncthreads();
    for (int d = 1; d < 256; d <<= 1) {
        const int u = (t >= d) ? p[t - d] : 0;
        __syncthreads();
        p[t] += u;
        __syncthreads();
    }
    if (t < NBUCK) {
        const int e = p[t] - v;     // exclusive
        bucketOff[t] = e;
        bcur[t] = e;
    }
    if (t == 0) bucketOff[NBUCK] = NE;
}

// ---------------- bin edges into 512-node buckets ----------------
__global__ __launch_bounds__(256) void bin_edges(const int* __restrict__ es,
                                                 const int* __restrict__ ed,
                                                 const float* __restrict__ ew,
                                                 int* __restrict__ bcur,
                                                 int2* __restrict__ srcw2b,
                                                 int* __restrict__ dstb) {
    __shared__ int hist[NBUCK];
    __shared__ int base[NBUCK];
    const int tid = threadIdx.x;
    const int e0 = blockIdx.x * 4096;
    for (int i = tid; i < NBUCK; i += 256) hist[i] = 0;
    __syncthreads();
    int d[16];
#pragma unroll
    for (int j = 0; j < 16; ++j) {
        const int e = e0 + j * 256 + tid;
        d[j] = (e < NE) ? ed[e] : -1;
        if (d[j] >= 0) atomicAdd(&hist[d[j] >> BSHIFT], 1);
    }
    __syncthreads();
    for (int i = tid; i < NBUCK; i += 256) base[i] = atomicAdd(&bcur[i], hist[i]);
    __syncthreads();
    for (int i = tid; i < NBUCK; i += 256) hist[i] = 0;
    __syncthreads();
#pragma unroll
    for (int j = 0; j < 16; ++j) {
        const int e = e0 + j * 256 + tid;
        if (d[j] >= 0) {
            const int b = d[j] >> BSHIFT;
            const int l = atomicAdd(&hist[b], 1);
            const int p = base[b] + l;
            srcw2b[p] = make_int2(es[e], __float_as_int(ew[e]));
            dstb[p] = d[j];
        }
    }
}

// ---------------- per-bucket CSR finalize: LDS hist + scan + place ----------------
__global__ __launch_bounds__(256) void bucket_csr(const int2* __restrict__ srcw2b,
                                                  const int* __restrict__ dstb,
                                                  const int* __restrict__ bucketOff,
                                                  int* __restrict__ off,
                                                  int2* __restrict__ edges2) {
    __shared__ int A[512], B[512];
    const int tid = threadIdx.x;
    const int b = blockIdx.x;
    const int beg = bucketOff[b];
    const int end = bucketOff[b + 1];
    const int nodeBase = b << BSHIFT;
    for (int i = tid; i < 512; i += 256) A[i] = 0;
    __syncthreads();
    for (int e = beg + tid; e < end; e += 256)
        atomicAdd(&A[dstb[e] - nodeBase], 1);
    __syncthreads();
    // inclusive scan over 512 (ping-pong Hillis-Steele)
    int* src = A;
    int* dst = B;
    for (int d = 1; d < 512; d <<= 1) {
        for (int i = tid; i < 512; i += 256)
            dst[i] = src[i] + ((i >= d) ? src[i - d] : 0);
        __syncthreads();
        int* t = src; src = dst; dst = t;
    }
    // write off[] and init LDS cursors (dst buffer reused as cursors)
    for (int i = tid; i < 512; i += 256) {
        const int excl = (i == 0) ? 0 : src[i - 1];
        dst[i] = excl;
        const int node = nodeBase + i;
        if (node < NN) off[node] = beg + excl;
    }
    if (b == 0 && tid == 0) off[NN] = NE;
    __syncthreads();
    // place edges within the bucket window (LDS cursor atomics only)
    for (int e = beg + tid; e < end; e += 256) {
        const int d = dstb[e] - nodeBase;
        const int pos = atomicAdd(&dst[d], 1);
        edges2[beg + pos] = srcw2b[e];
    }
}

// ---------------- CSR SpMM (bf16 gather, 2 edges/instr) + bias + relu ----------------
__global__ __launch_bounds__(256) void spmm_csr(const __hip_bfloat16* __restrict__ feat,
                                                const int* __restrict__ off,
                                                const int2* __restrict__ edges2,
                                                const float* __restrict__ b,
                                                float* __restrict__ out) {
    const int w = threadIdx.x >> 6;
    const int lane = threadIdx.x & 63;
    const int n = blockIdx.x * 4 + w;
    const int beg = off[n];
    const int end = off[n + 1];
    const int p = lane >> 5;
    const int f2 = lane & 31;
    float ax = 0.f, ay = 0.f;
    int i = beg;
    for (; i + 7 < end; i += 8) {
        const int2 e0 = edges2[i     + p];
        const int2 e1 = edges2[i + 2 + p];
        const int2 e2 = edges2[i + 4 + p];
        const int2 e3 = edges2[i + 6 + p];
        const unsigned g0 = *(const unsigned*)(feat + (size_t)e0.x * 64 + f2 * 2);
        const unsigned g1 = *(const unsigned*)(feat + (size_t)e1.x * 64 + f2 * 2);
        const unsigned g2 = *(const unsigned*)(feat + (size_t)e2.x * 64 + f2 * 2);
        const unsigned g3 = *(const unsigned*)(feat + (size_t)e3.x * 64 + f2 * 2);
        const float w0 = __int_as_float(e0.y), w1 = __int_as_float(e1.y);
        const float w2 = __int_as_float(e2.y), w3 = __int_as_float(e3.y);
        ax = fmaf(__uint_as_float(g0 << 16), w0, ax);
        ay = fmaf(__uint_as_float(g0 & 0xffff0000u), w0, ay);
        ax = fmaf(__uint_as_float(g1 << 16), w1, ax);
        ay = fmaf(__uint_as_float(g1 & 0xffff0000u), w1, ay);
        ax = fmaf(__uint_as_float(g2 << 16), w2, ax);
        ay = fmaf(__uint_as_float(g2 & 0xffff0000u), w2, ay);
        ax = fmaf(__uint_as_float(g3 << 16), w3, ax);
        ay = fmaf(__uint_as_float(g3 & 0xffff0000u), w3, ay);
    }
    for (; i + 1 < end; i += 2) {
        const int2 e = edges2[i + p];
        const unsigned g = *(const unsigned*)(feat + (size_t)e.x * 64 + f2 * 2);
        const float wv = __int_as_float(e.y);
        ax = fmaf(__uint_as_float(g << 16), wv, ax);
        ay = fmaf(__uint_as_float(g & 0xffff0000u), wv, ay);
    }
    if (i < end && p == 0) {
        const int2 e = edges2[i];
        const unsigned g = *(const unsigned*)(feat + (size_t)e.x * 64 + f2 * 2);
        const float wv = __int_as_float(e.y);
        ax = fmaf(__uint_as_float(g << 16), wv, ax);
        ay = fmaf(__uint_as_float(g & 0xffff0000u), wv, ay);
    }
    ax += __shfl_xor(ax, 32, 64);
    ay += __shfl_xor(ay, 32, 64);
    if (p == 0) {
        float vx = ax + b[f2 * 2];
        float vy = ay + b[f2 * 2 + 1];
        vx = vx > 0.f ? vx : 0.f;
        vy = vy > 0.f ? vy : 0.f;
        *(float2*)(out + (size_t)n * 64 + f2 * 2) = make_float2(vx, vy);
    }
}

// ============ head: 128 rows x 40 cols per block, register-tiled ============
__global__ __launch_bounds__(256) void head_tile(const float* __restrict__ h2,
                                                 const float* __restrict__ Wl,
                                                 const float* __restrict__ bl,
                                                 float* __restrict__ logits,
                                                 float* __restrict__ logp) {
    __shared__ float Wt[40 * 68];      // 10880 B
    __shared__ float Xs[HROWS * 68];   // 34816 B
    __shared__ float bs[40];
    const int tid = threadIdx.x;
    const int row0 = blockIdx.x * HROWS;
    for (int i = tid; i < 64 * 40; i += 256) {
        const int k = i / 40, c = i - k * 40;
        Wt[c * 68 + k] = Wl[i];
    }
    if (tid < 40) bs[tid] = bl[tid];
    for (int i = tid; i < HROWS * 16; i += 256) {
        const int r = i >> 4, kq = i & 15;
        const int row = row0 + r;
        float4 v = make_float4(0.f, 0.f, 0.f, 0.f);
        if (row < NN) v = *(const float4*)(h2 + (size_t)row * 64 + kq * 4);
        *(float4*)(&Xs[r * 68 + kq * 4]) = v;
    }
    __syncthreads();
    const int tcol = tid & 3;
    const int trow = tid >> 2;
    float acc[2][10] = {};
    const float* xb0 = &Xs[trow * 68];
    const float* xb1 = &Xs[(trow + 64) * 68];
    const float* wb = &Wt[(tcol * 10) * 68];
    for (int k = 0; k < 64; k += 4) {
        const float4 x0 = *(const float4*)(xb0 + k);
        const float4 x1 = *(const float4*)(xb1 + k);
#pragma unroll
        for (int c = 0; c < 10; ++c) {
            const float4 wv = *(const float4*)(wb + c * 68 + k);
            acc[0][c] = fmaf(x0.x, wv.x, acc[0][c]);
            acc[0][c] = fmaf(x0.y, wv.y, acc[0][c]);
            acc[0][c] = fmaf(x0.z, wv.z, acc[0][c]);
            acc[0][c] = fmaf(x0.w, wv.w, acc[0][c]);
            acc[1][c] = fmaf(x1.x, wv.x, acc[1][c]);
            acc[1][c] = fmaf(x1.y, wv.y, acc[1][c]);
            acc[1][c] = fmaf(x1.z, wv.z, acc[1][c]);
            acc[1][c] = fmaf(x1.w, wv.w, acc[1][c]);
        }
    }
    float bv[10];
#pragma unroll
    for (int c = 0; c < 10; ++c) bv[c] = bs[tcol * 10 + c];
#pragma unroll
    for (int r = 0; r < 2; ++r) {
        const int row = row0 + trow + r * 64;
#pragma unroll
        for (int c = 0; c < 10; ++c) acc[r][c] += bv[c];
        float m = acc[r][0];
#pragma unroll
        for (int c = 1; c < 10; ++c) m = fmaxf(m, acc[r][c]);
        m = fmaxf(m, __shfl_xor(m, 1, 64));
        m = fmaxf(m, __shfl_xor(m, 2, 64));
        float s = 0.f;
#pragma unroll
        for (int c = 0; c < 10; ++c) s += expf(acc[r][c] - m);
        s += __shfl_xor(s, 1, 64);
        s += __shfl_xor(s, 2, 64);
        const float lse = logf(s) + m;
        if (row < NN) {
            float* lg = logits + (size_t)row * 40 + tcol * 10;
            float* lp = logp   + (size_t)row * 40 + tcol * 10;
#pragma unroll
            for (int c = 0; c < 10; c += 2) {
                *(float2*)(lg + c) = make_float2(acc[r][c], acc[r][c + 1]);
                *(float2*)(lp + c) = make_float2(acc[r][c] - lse, acc[r][c + 1] - lse);
            }
        }
    }
}

extern "C" void kernel_launch(void* const* d_in, const int* in_sizes, int n_in,
                              void* d_out, int out_size, void* d_ws, size_t ws_size,
                              hipStream_t stream) {
    const float* x  = (const float*)d_in[0];
    const int*   es = (const int*)  d_in[1];
    const int*   ed = (const int*)  d_in[2];
    const float* ew = (const float*)d_in[3];
    const float* W1 = (const float*)d_in[4];
    const float* b1 = (const float*)d_in[5];
    const float* W2 = (const float*)d_in[6];
    const float* b2 = (const float*)d_in[7];
    const float* Wl = (const float*)d_in[8];
    const float* bl = (const float*)d_in[9];

    float* out    = (float*)d_out;
    float* logp   = out;                          // [N,40]
    float* h1     = logp + (size_t)NN * 40;       // [N,64]
    float* h2     = h1   + (size_t)NN * 64;       // [N,64]
    float* logits = h2   + (size_t)NN * 64;       // [N,40]

    // workspace layout
    char* wsb = (char*)d_ws;
    __hip_bfloat16* ws0 = (__hip_bfloat16*)wsb;                 // [N,64] bf16 (GEMM out)
    int2*  srcw2b   = (int2*)wsb;                               // binned edges (overlays ws0)
    int*   dstb     = (int*)(wsb + (size_t)NE * 8);             // binned dsts
    int2*  edges2   = (int2*)(wsb + (size_t)NN * 64 * 4);       // [E] 12.8 MB
    int*   off      = (int*)((char*)edges2 + (size_t)NE * 8);   // [N+1]
    int*   bucketCnt = off + (NN + 1);                          // [NBUCK]
    int*   bucketOff = bucketCnt + NBUCK;                       // [NBUCK+1]
    int*   bcur      = bucketOff + (NBUCK + 1);                 // [NBUCK]

    const int gemmGrid = (NN + 63) / 64;
    const int edgeGrid = (NE + 4095) / 4096;      // 391

    // ---- build dest-sorted CSR (no node-level global atomics) ----
    hipMemsetAsync(bucketCnt, 0, (size_t)NBUCK * 4, stream);
    bucket_hist<<<edgeGrid, 256, 0, stream>>>(ed, bucketCnt);
    bucket_scan<<<1, 256, 0, stream>>>(bucketCnt, bucketOff, bcur);
    bin_edges<<<edgeGrid, 256, 0, stream>>>(es, ed, ew, bcur, srcw2b, dstb);
    bucket_csr<<<NBUCK, 256, 0, stream>>>(srcw2b, dstb, bucketOff, off, edges2);

    // ---- layer 1 ----
    gemm1_tile<<<gemmGrid, 256, 0, stream>>>(x, W1, ws0);
    spmm_csr<<<NN / 4, 256, 0, stream>>>(ws0, off, edges2, b1, h1);

    // ---- layer 2 ----
    gemm2_tile<<<gemmGrid, 256, 0, stream>>>(h1, W2, ws0);
    spmm_csr<<<NN / 4, 256, 0, stream>>>(ws0, off, edges2, b2, h2);

    // ---- head ----
    head_tile<<<(NN + HROWS - 1) / HROWS, 256, 0, stream>>>(h2, Wl, bl, logits, logp);
}